// Round 5
// baseline (2556.452 us; speedup 1.0000x reference)
//
#include <hip/hip_runtime.h>
#include <hip/hip_bf16.h>

#define Bq 2
#define Cc 64
#define Hh 48
#define Ww 48
#define Ll 2304
#define NHh 8
#define DKk 64
#define DVv 128
#define DNn 128
#define NSs 16
#define Rr 4

// ---- workspace layout (float offsets) ----
#define OQ    0u
#define OK_   2359296u
#define OV    4718592u
#define OO    9437184u
#define OXH   14155776u
#define OY2   14450688u
#define OX2   15040512u
#define OXN   15335424u
// aliases (lifetimes verified: q,k,v,o dead before reuse)
#define ODT   OQ                 // (B,4,DN,L)
#define OYS   OK_                // (B,4,DN,L)
#define OH1A  OV                 // (B,L,256)
#define OH1B  (OV + 1179648u)    // (B,L,256)
#define OX1P  OO                 // (B,L,128)
#define OZ    (OO + 589824u)     // (B,L,128)
#define OX1S  (OO + 1179648u)    // (B,L,128)
#define OBS   (OO + 1769472u)    // (B,4,NS,L)
#define OCS   (OO + 2064384u)    // (B,4,NS,L)
#define OX3   (OO + 2359296u)    // (B,L,64)

__device__ __forceinline__ float geluf(float x) {
  return 0.5f * x * (1.0f + erff(x * 0.70710678118654752f));
}
__device__ __forceinline__ float siluf(float x) {
  return x / (1.0f + __expf(-x));
}
__device__ __forceinline__ float softplusf(float x) {
  return fmaxf(x, 0.0f) + log1pf(__expf(-fabsf(x)));
}

// ============ 1. QKV projection ============
__global__ __launch_bounds__(256) void k_qkv(const float* __restrict__ enc,
    const float* __restrict__ wq, const float* __restrict__ wk,
    const float* __restrict__ wv, float* __restrict__ ws) {
  int bl = blockIdx.x; int b = bl / Ll; int l = bl % Ll;
  int t = threadIdx.x;
  __shared__ float xr[64];
  if (t < 64) xr[t] = enc[(size_t)b * Cc * Ll + (size_t)t * Ll + l];
  __syncthreads();
  float* q = ws + OQ; float* k = ws + OK_; float* v = ws + OV;
#pragma unroll
  for (int i = 0; i < 8; ++i) {
    int j = t + i * 256;
    float acc = 0.f;
    if (j < 512) {
      const float* wp = wq; int col = j;
#pragma unroll 8
      for (int c = 0; c < 64; ++c) acc += xr[c] * wp[c * 512 + col];
      q[((size_t)(b * 8 + (col >> 6)) * Ll + l) * 64 + (col & 63)] = acc;
    } else if (j < 1024) {
      const float* wp = wk; int col = j - 512;
#pragma unroll 8
      for (int c = 0; c < 64; ++c) acc += xr[c] * wp[c * 512 + col];
      k[((size_t)(b * 8 + (col >> 6)) * Ll + l) * 64 + (col & 63)] = acc;
    } else {
      const float* wp = wv; int col = j - 1024;
#pragma unroll 8
      for (int c = 0; c < 64; ++c) acc += xr[c] * wp[c * 1024 + col];
      v[((size_t)(b * 8 + (col >> 7)) * Ll + l) * 128 + (col & 127)] = acc;
    }
  }
}

// ============ 2. flash attention (fp32 VALU) ============
#define QT 64
#define TKK 32
__global__ __launch_bounds__(256) void k_attn(const float* __restrict__ snr,
                                              float* __restrict__ ws) {
  int bh = blockIdx.y; int b = bh >> 3; int hd = bh & 7;
  int q0 = blockIdx.x * QT;
  int t = threadIdx.x;
  __shared__ float Qs[QT * 64];
  __shared__ float Ks[TKK * 65];
  __shared__ float4 Vs[TKK * 32];
  __shared__ float Ss[QT * 33];
  __shared__ float arow[QT], lrow[QT], lsn[TKK];
  const float* qp = ws + OQ + ((size_t)bh * Ll + q0) * 64;
  for (int i = t; i < QT * 64; i += 256) Qs[i] = qp[i];
  float m_r = -1e30f, l_r = 0.f;
  int rg = t >> 5, dvq = t & 31; int r0 = rg * 8;
  float4 Oa[8];
#pragma unroll
  for (int i = 0; i < 8; ++i) Oa[i] = make_float4(0.f, 0.f, 0.f, 0.f);
  int r = t >> 2, kb = (t & 3) * 8;
  for (int kt = 0; kt < Ll / TKK; ++kt) {
    int k0 = kt * TKK;
    const float* kp = ws + OK_ + ((size_t)bh * Ll + k0) * 64;
    for (int i = t; i < TKK * 64; i += 256) Ks[(i >> 6) * 65 + (i & 63)] = kp[i];
    const float4* vp = (const float4*)(ws + OV + ((size_t)bh * Ll + k0) * 128);
    for (int i = t; i < TKK * 32; i += 256) Vs[i] = vp[i];
    if (t < TKK) lsn[t] = logf(snr[b * Ll + k0 + t] + 1e-4f);
    __syncthreads();
    float acc[8];
#pragma unroll
    for (int i = 0; i < 8; ++i) acc[i] = 0.f;
    for (int d = 0; d < 64; ++d) {
      float qv = Qs[r * 64 + d];
#pragma unroll
      for (int i = 0; i < 8; ++i) acc[i] += qv * Ks[(kb + i) * 65 + d];
    }
#pragma unroll
    for (int i = 0; i < 8; ++i) Ss[r * 33 + kb + i] = acc[i] * 0.125f + lsn[kb + i];
    __syncthreads();
    if (t < QT) {
      float mx = m_r;
      for (int kk = 0; kk < TKK; ++kk) mx = fmaxf(mx, Ss[t * 33 + kk]);
      float al = __expf(m_r - mx);
      float s = 0.f;
      for (int kk = 0; kk < TKK; ++kk) {
        float p = __expf(Ss[t * 33 + kk] - mx);
        Ss[t * 33 + kk] = p; s += p;
      }
      l_r = l_r * al + s; m_r = mx; arow[t] = al;
    }
    __syncthreads();
#pragma unroll
    for (int ii = 0; ii < 8; ++ii) {
      float a = arow[r0 + ii];
      Oa[ii].x *= a; Oa[ii].y *= a; Oa[ii].z *= a; Oa[ii].w *= a;
    }
    for (int kk = 0; kk < TKK; ++kk) {
      float4 v4 = Vs[kk * 32 + dvq];
#pragma unroll
      for (int ii = 0; ii < 8; ++ii) {
        float p = Ss[(r0 + ii) * 33 + kk];
        Oa[ii].x += p * v4.x; Oa[ii].y += p * v4.y;
        Oa[ii].z += p * v4.z; Oa[ii].w += p * v4.w;
      }
    }
    __syncthreads();
  }
  if (t < QT) lrow[t] = l_r;
  __syncthreads();
  float* op = ws + OO + ((size_t)b * Ll + q0) * 1024 + hd * 128;
#pragma unroll
  for (int ii = 0; ii < 8; ++ii) {
    float inv = 1.f / lrow[r0 + ii];
    float4 o4 = make_float4(Oa[ii].x * inv, Oa[ii].y * inv,
                            Oa[ii].z * inv, Oa[ii].w * inv);
    *((float4*)(op + (size_t)(r0 + ii) * 1024) + dvq) = o4;
  }
}

// ============ 3. o@fc + residual + LN -> xh ============
__global__ __launch_bounds__(64) void k_oproj(const float* __restrict__ enc,
    const float* __restrict__ fc, const float* __restrict__ lnw,
    const float* __restrict__ lnb, float* __restrict__ ws) {
  int l = blockIdx.x, b = blockIdx.y, t = threadIdx.x;
  __shared__ float orow[1024];
  const float* op = ws + OO + ((size_t)b * Ll + l) * 1024;
  for (int i = t; i < 1024; i += 64) orow[i] = op[i];
  __syncthreads();
  float acc = 0.f;
#pragma unroll 4
  for (int j = 0; j < 1024; ++j) acc += orow[j] * fc[j * 64 + t];
  acc += enc[(size_t)b * Cc * Ll + (size_t)t * Ll + l];
  float s = acc;
#pragma unroll
  for (int o = 32; o >= 1; o >>= 1) s += __shfl_xor(s, o, 64);
  float m = s * (1.f / 64.f);
  float dd = acc - m;
  float vs = dd * dd;
#pragma unroll
  for (int o = 32; o >= 1; o >>= 1) vs += __shfl_xor(vs, o, 64);
  float var = vs * (1.f / 64.f);
  float y = dd * rsqrtf(var + 1e-5f) * lnw[t] + lnb[t];
  ws[OXH + ((size_t)b * Ll + l) * 64 + t] = y;
}

// ============ 4. xz = xh @ ss_in_w ============
__global__ __launch_bounds__(256) void k_xz(const float* __restrict__ ssin,
                                            float* __restrict__ ws) {
  int l = blockIdx.x, b = blockIdx.y, t = threadIdx.x;
  __shared__ float xr[64];
  if (t < 64) xr[t] = ws[OXH + ((size_t)b * Ll + l) * 64 + t];
  __syncthreads();
  float acc = 0.f;
#pragma unroll 8
  for (int c = 0; c < 64; ++c) acc += xr[c] * ssin[c * 256 + t];
  if (t < 128) ws[OX1P + ((size_t)b * Ll + l) * 128 + t] = acc;
  else ws[OZ + ((size_t)b * Ll + l) * 128 + (t - 128)] = acc;
}

// ============ 5. depthwise conv3x3 + bias + silu ============
__global__ __launch_bounds__(128) void k_conv(const float* __restrict__ cw,
    const float* __restrict__ cb, float* __restrict__ ws) {
  int l = blockIdx.x, b = blockIdx.y, d = threadIdx.x;
  int h = l / 48, w = l % 48;
  float acc = cb[d];
#pragma unroll
  for (int kh = 0; kh < 3; ++kh) {
    int hh = h + kh - 1;
    if (hh < 0 || hh >= 48) continue;
#pragma unroll
    for (int kw = 0; kw < 3; ++kw) {
      int wx = w + kw - 1;
      if (wx < 0 || wx >= 48) continue;
      acc += ws[OX1P + ((size_t)b * Ll + hh * 48 + wx) * 128 + d] *
             cw[d * 9 + kh * 3 + kw];
    }
  }
  ws[OX1S + ((size_t)b * Ll + l) * 128 + d] = siluf(acc);
}

// ============ 6. x_dbl projections: dt, Bs, Cs ============
__global__ __launch_bounds__(128) void k_xdbl(const float* __restrict__ xw,
    const float* __restrict__ dtw, const float* __restrict__ dtb,
    float* __restrict__ ws) {
  int l = blockIdx.x;
  int by = blockIdx.y; int b = by >> 2; int k = by & 3;
  int t = threadIdx.x;
  int sp;
  if (k == 0) sp = l;
  else if (k == 1) sp = (l % 48) * 48 + l / 48;
  else if (k == 2) sp = 2303 - l;
  else { int l2 = 2303 - l; sp = (l2 % 48) * 48 + l2 / 48; }
  __shared__ float xv[128];
  __shared__ float pr[36];
  xv[t] = ws[OX1S + ((size_t)b * Ll + sp) * 128 + t];
  __syncthreads();
  if (t < 36) {
    float s = 0.f;
    const float* wp = xw + (size_t)(k * 36 + t) * 128;
#pragma unroll 8
    for (int d = 0; d < 128; ++d) s += xv[d] * wp[d];
    pr[t] = s;
  }
  __syncthreads();
  {
    int d = t;
    const float* wp = dtw + (size_t)(k * 128 + d) * 4;
    float v = pr[0] * wp[0] + pr[1] * wp[1] +
              pr[2] * wp[2] + pr[3] * wp[3] + dtb[k * 128 + d];
    ws[ODT + ((size_t)((b * 4 + k) * 128 + d)) * 2304 + l] = softplusf(v);
  }
  if (t < 16) ws[OBS + ((size_t)((b * 4 + k) * 16 + t)) * 2304 + l] = pr[4 + t];
  else if (t < 32) ws[OCS + ((size_t)((b * 4 + k) * 16 + (t - 16))) * 2304 + l] = pr[20 + (t - 16)];
}

// ============ 7. selective scan ============
__global__ __launch_bounds__(256) void k_scan(const float* __restrict__ alog,
    const float* __restrict__ Dp, float* __restrict__ ws) {
  int idx = blockIdx.x;
  int b = idx / 32; int rem = idx % 32; int k = rem / 8; int dblk = rem % 8;
  int t = threadIdx.x;
  int d = dblk * 16 + (t >> 4);
  int n = t & 15;
  float A = -__expf(alog[(size_t)((k * 128 + d) * 16) + n]);
  float Dv = Dp[k * 128 + d];
  const float* dtp = ws + ODT + ((size_t)((b * 4 + k) * 128 + d)) * 2304;
  const float* bp = ws + OBS + ((size_t)((b * 4 + k) * 16 + n)) * 2304;
  const float* cp = ws + OCS + ((size_t)((b * 4 + k) * 16 + n)) * 2304;
  const float* xbase = ws + OX1S + (size_t)b * Ll * 128 + d;
  float* yp = ws + OYS + ((size_t)((b * 4 + k) * 128 + d)) * 2304;
  float hst = 0.f;
  for (int l = 0; l < Ll; ++l) {
    int sp;
    if (k == 0) sp = l;
    else if (k == 1) sp = (l % 48) * 48 + l / 48;
    else if (k == 2) sp = 2303 - l;
    else { int l2 = 2303 - l; sp = (l2 % 48) * 48 + l2 / 48; }
    float x = xbase[(size_t)sp * 128];
    float dtv = dtp[l];
    float Bt = bp[l];
    float Ct = cp[l];
    hst = hst * __expf(dtv * A) + (dtv * x) * Bt;
    float yv = hst * Ct;
    yv += __shfl_xor(yv, 1, 64);
    yv += __shfl_xor(yv, 2, 64);
    yv += __shfl_xor(yv, 4, 64);
    yv += __shfl_xor(yv, 8, 64);
    if (n == 0) yp[l] = yv + Dv * x;
  }
}

// ============ 8. combine dirs + LN + gate ============
__global__ __launch_bounds__(128) void k_comb(const float* __restrict__ nw,
    const float* __restrict__ nb, const float* __restrict__ snr,
    float* __restrict__ ws) {
  int l = blockIdx.x, b = blockIdx.y, d = threadIdx.x;
  int h = l / 48, w = l % 48;
  int lT = w * 48 + h;
  const float* ysb = ws + OYS;
  float v = ysb[((size_t)((b * 4 + 0) * 128 + d)) * 2304 + l] +
            ysb[((size_t)((b * 4 + 2) * 128 + d)) * 2304 + (2303 - l)] +
            ysb[((size_t)((b * 4 + 1) * 128 + d)) * 2304 + lT] +
            ysb[((size_t)((b * 4 + 3) * 128 + d)) * 2304 + (2303 - lT)];
  __shared__ float red[4];
  int lane = d & 63, wid = d >> 6;
  float s = v;
#pragma unroll
  for (int o = 32; o >= 1; o >>= 1) s += __shfl_xor(s, o, 64);
  if (lane == 0) red[wid] = s;
  __syncthreads();
  float m = (red[0] + red[1]) * (1.f / 128.f);
  float dv_ = v - m;
  float q = dv_ * dv_;
#pragma unroll
  for (int o = 32; o >= 1; o >>= 1) q += __shfl_xor(q, o, 64);
  if (lane == 0) red[wid + 2] = q;
  __syncthreads();
  float var = (red[2] + red[3]) * (1.f / 128.f);
  float y = dv_ * rsqrtf(var + 1e-5f) * nw[d] + nb[d];
  float zv = ws[OZ + ((size_t)b * Ll + l) * 128 + d];
  y *= siluf(zv);
  y *= snr[b * Ll + l];
  ws[OY2 + ((size_t)b * Ll + l) * 128 + d] = y;
}

// ============ 9. x2 = y2@out_w + enc residual; LN -> xn ============
__global__ __launch_bounds__(64) void k_outln(const float* __restrict__ enc,
    const float* __restrict__ ow, const float* __restrict__ lw,
    const float* __restrict__ lb, float* __restrict__ ws) {
  int l = blockIdx.x, b = blockIdx.y, c = threadIdx.x;
  __shared__ float yr[128];
  const float* yp = ws + OY2 + ((size_t)b * Ll + l) * 128;
  yr[c] = yp[c]; yr[c + 64] = yp[c + 64];
  __syncthreads();
  float acc = 0.f;
#pragma unroll 8
  for (int dd = 0; dd < 128; ++dd) acc += yr[dd] * ow[dd * 64 + c];
  acc += enc[(size_t)b * Cc * Ll + (size_t)c * Ll + l];
  ws[OX2 + ((size_t)b * Ll + l) * 64 + c] = acc;
  float s = acc;
#pragma unroll
  for (int o = 32; o >= 1; o >>= 1) s += __shfl_xor(s, o, 64);
  float m = s * (1.f / 64.f);
  float dd2 = acc - m;
  float vs = dd2 * dd2;
#pragma unroll
  for (int o = 32; o >= 1; o >>= 1) vs += __shfl_xor(vs, o, 64);
  float var = vs * (1.f / 64.f);
  float y = dd2 * rsqrtf(var + 1e-5f) * lw[c] + lb[c];
  ws[OXN + ((size_t)b * Ll + l) * 64 + c] = y;
}

// ============ 10. FFN conv1 1x1 + gelu ============
__global__ __launch_bounds__(256) void k_ffn1(const float* __restrict__ w1,
                                              float* __restrict__ ws) {
  int l = blockIdx.x, b = blockIdx.y, mch = threadIdx.x;
  __shared__ float xr[64];
  if (mch < 64) xr[mch] = ws[OXN + ((size_t)b * Ll + l) * 64 + mch];
  __syncthreads();
  float acc = 0.f;
  const float* wp = w1 + (size_t)mch * 64;
#pragma unroll 8
  for (int c = 0; c < 64; ++c) acc += xr[c] * wp[c];
  ws[OH1A + ((size_t)b * Ll + l) * 256 + mch] = geluf(acc);
}

// ============ 11. FFN depthwise 3x3 + gelu ============
__global__ __launch_bounds__(256) void k_ffndw(const float* __restrict__ dww,
                                               float* __restrict__ ws) {
  int l = blockIdx.x, b = blockIdx.y, mch = threadIdx.x;
  int h = l / 48, w = l % 48;
  float acc = 0.f;
#pragma unroll
  for (int kh = 0; kh < 3; ++kh) {
    int hh = h + kh - 1;
    if (hh < 0 || hh >= 48) continue;
#pragma unroll
    for (int kw = 0; kw < 3; ++kw) {
      int wx = w + kw - 1;
      if (wx < 0 || wx >= 48) continue;
      acc += ws[OH1A + ((size_t)b * Ll + hh * 48 + wx) * 256 + mch] *
             dww[mch * 9 + kh * 3 + kw];
    }
  }
  ws[OH1B + ((size_t)b * Ll + l) * 256 + mch] = geluf(acc);
}

// ============ 12. FFN conv2 1x1 + residual ============
__global__ __launch_bounds__(64) void k_ffn2(const float* __restrict__ w2,
                                             float* __restrict__ ws) {
  int l = blockIdx.x, b = blockIdx.y, c = threadIdx.x;
  __shared__ float hr[256];
  const float* hp = ws + OH1B + ((size_t)b * Ll + l) * 256;
  for (int i = c; i < 256; i += 64) hr[i] = hp[i];
  __syncthreads();
  float acc = 0.f;
  const float* wp = w2 + (size_t)c * 256;
#pragma unroll 8
  for (int mm = 0; mm < 256; ++mm) acc += hr[mm] * wp[mm];
  acc += ws[OX2 + ((size_t)b * Ll + l) * 64 + c];
  ws[OX3 + ((size_t)b * Ll + l) * 64 + c] = acc;
}

// ============ 13. transpose (B,L,C) -> (B,C,L) fp32 out ============
__global__ __launch_bounds__(256) void k_trout(const float* __restrict__ ws,
                                               float* __restrict__ out) {
  int b = blockIdx.y;
  int l0 = blockIdx.x * 64;
  int t = threadIdx.x;
  __shared__ float tile[64][65];
  const float* xp = ws + OX3 + ((size_t)b * Ll + l0) * 64;
  for (int i = t; i < 4096; i += 256) tile[i >> 6][i & 63] = xp[i];
  __syncthreads();
  for (int i = t; i < 4096; i += 256) {
    int c = i >> 6, li = i & 63;
    out[((size_t)(b * 64 + c)) * 2304 + l0 + li] = tile[li][c];
  }
}

extern "C" void kernel_launch(void* const* d_in, const int* in_sizes, int n_in,
                              void* d_out, int out_size, void* d_ws, size_t ws_size,
                              hipStream_t stream) {
  (void)in_sizes; (void)n_in; (void)out_size; (void)ws_size;
  const float* enc  = (const float*)d_in[0];
  const float* snr  = (const float*)d_in[1];
  const float* wq   = (const float*)d_in[2];
  const float* wk   = (const float*)d_in[3];
  const float* wv   = (const float*)d_in[4];
  const float* fc   = (const float*)d_in[5];
  const float* alnw = (const float*)d_in[6];
  const float* alnb = (const float*)d_in[7];
  const float* ssin = (const float*)d_in[8];
  const float* cw   = (const float*)d_in[9];
  const float* cb   = (const float*)d_in[10];
  const float* xw   = (const float*)d_in[11];
  const float* dtw  = (const float*)d_in[12];
  const float* dtb  = (const float*)d_in[13];
  const float* alog = (const float*)d_in[14];
  const float* Dp   = (const float*)d_in[15];
  const float* nw   = (const float*)d_in[16];
  const float* nb   = (const float*)d_in[17];
  const float* ow   = (const float*)d_in[18];
  const float* flnw = (const float*)d_in[19];
  const float* flnb = (const float*)d_in[20];
  const float* w1   = (const float*)d_in[21];
  const float* dww  = (const float*)d_in[22];
  const float* w2   = (const float*)d_in[23];
  float* ws = (float*)d_ws;
  float* out = (float*)d_out;

  hipLaunchKernelGGL(k_qkv, dim3(Bq * Ll), dim3(256), 0, stream, enc, wq, wk, wv, ws);
  hipLaunchKernelGGL(k_attn, dim3(Ll / QT, Bq * NHh), dim3(256), 0, stream, snr, ws);
  hipLaunchKernelGGL(k_oproj, dim3(Ll, Bq), dim3(64), 0, stream, enc, fc, alnw, alnb, ws);
  hipLaunchKernelGGL(k_xz, dim3(Ll, Bq), dim3(256), 0, stream, ssin, ws);
  hipLaunchKernelGGL(k_conv, dim3(Ll, Bq), dim3(128), 0, stream, cw, cb, ws);
  hipLaunchKernelGGL(k_xdbl, dim3(Ll, Bq * 4), dim3(128), 0, stream, xw, dtw, dtb, ws);
  hipLaunchKernelGGL(k_scan, dim3(64), dim3(256), 0, stream, alog, Dp, ws);
  hipLaunchKernelGGL(k_comb, dim3(Ll, Bq), dim3(128), 0, stream, nw, nb, snr, ws);
  hipLaunchKernelGGL(k_outln, dim3(Ll, Bq), dim3(64), 0, stream, enc, ow, flnw, flnb, ws);
  hipLaunchKernelGGL(k_ffn1, dim3(Ll, Bq), dim3(256), 0, stream, w1, ws);
  hipLaunchKernelGGL(k_ffndw, dim3(Ll, Bq), dim3(256), 0, stream, dww, ws);
  hipLaunchKernelGGL(k_ffn2, dim3(Ll, Bq), dim3(64), 0, stream, w2, ws);
  hipLaunchKernelGGL(k_trout, dim3(Ll / 64, Bq), dim3(256), 0, stream, ws, out);
}

// Round 6
// 1529.102 us; speedup vs baseline: 1.6719x; 1.6719x over previous
//
#include <hip/hip_runtime.h>
#include <hip/hip_bf16.h>

#define Bq 2
#define Cc 64
#define Hh 48
#define Ww 48
#define Ll 2304
#define NHh 8
#define DKk 64
#define DVv 128
#define DNn 128
#define NSs 16
#define Rr 4
#define SCH 48   // scan chunk length
#define SNC 48   // number of chunks (SCH*SNC = Ll)

// ---- workspace layout (float offsets) ----
#define OQ    0u
#define OK_   2359296u
#define OV    4718592u
#define OO    9437184u
#define OXH   14155776u
#define OY2   14450688u
#define OX2   15040512u
#define OXN   15335424u
// aliases (lifetimes: q,k,v dead after k_attn; o dead after k_oproj)
#define ODT2  OQ                 // (B*4, L, 128) dt, l-major
#define OYS2  OK_                // (B*4, L, 128) scan y, l-major
#define OX1P  OV                 // (B,L,128)
#define OZ    (OV + 589824u)     // (B,L,128)
#define OX1S  (OV + 1179648u)    // (B,L,128)
#define OBS2  (OV + 1769472u)    // (B*4, L, 16)
#define OCS2  (OV + 2064384u)    // (B*4, L, 16)
#define OCSA  (OV + 2359296u)    // (B*4, SNC, 128, 16) chunk A-product
#define OCSB  (OV + 3145728u)    // (B*4, SNC, 128, 16) chunk B-composite
#define OHST  (OV + 3932160u)    // (B*4, SNC, 128, 16) chunk start state
#define OH1A  OO                 // (B,L,256)
#define OH1B  (OO + 1179648u)    // (B,L,256)
#define OX3   (OO + 2359296u)    // (B,L,64)

__device__ __forceinline__ float geluf(float x) {
  return 0.5f * x * (1.0f + erff(x * 0.70710678118654752f));
}
__device__ __forceinline__ float siluf(float x) {
  return x / (1.0f + __expf(-x));
}
__device__ __forceinline__ float softplusf(float x) {
  return fmaxf(x, 0.0f) + log1pf(__expf(-fabsf(x)));
}
__device__ __forceinline__ int spmap(int k, int l) {
  if (k == 0) return l;
  if (k == 1) return (l % 48) * 48 + l / 48;
  if (k == 2) return 2303 - l;
  int l2 = 2303 - l; return (l2 % 48) * 48 + l2 / 48;
}

// ============ 1. QKV projection ============
__global__ __launch_bounds__(256) void k_qkv(const float* __restrict__ enc,
    const float* __restrict__ wq, const float* __restrict__ wk,
    const float* __restrict__ wv, float* __restrict__ ws) {
  int bl = blockIdx.x; int b = bl / Ll; int l = bl % Ll;
  int t = threadIdx.x;
  __shared__ float xr[64];
  if (t < 64) xr[t] = enc[(size_t)b * Cc * Ll + (size_t)t * Ll + l];
  __syncthreads();
  float* q = ws + OQ; float* k = ws + OK_; float* v = ws + OV;
#pragma unroll
  for (int i = 0; i < 8; ++i) {
    int j = t + i * 256;
    float acc = 0.f;
    if (j < 512) {
      const float* wp = wq; int col = j;
#pragma unroll 8
      for (int c = 0; c < 64; ++c) acc += xr[c] * wp[c * 512 + col];
      q[((size_t)(b * 8 + (col >> 6)) * Ll + l) * 64 + (col & 63)] = acc;
    } else if (j < 1024) {
      const float* wp = wk; int col = j - 512;
#pragma unroll 8
      for (int c = 0; c < 64; ++c) acc += xr[c] * wp[c * 512 + col];
      k[((size_t)(b * 8 + (col >> 6)) * Ll + l) * 64 + (col & 63)] = acc;
    } else {
      const float* wp = wv; int col = j - 1024;
#pragma unroll 8
      for (int c = 0; c < 64; ++c) acc += xr[c] * wp[c * 1024 + col];
      v[((size_t)(b * 8 + (col >> 7)) * Ll + l) * 128 + (col & 127)] = acc;
    }
  }
}

// ============ 2. flash attention (fp32 VALU) ============
#define QT 64
#define TKK 32
__global__ __launch_bounds__(256) void k_attn(const float* __restrict__ snr,
                                              float* __restrict__ ws) {
  int bh = blockIdx.y; int b = bh >> 3; int hd = bh & 7;
  int q0 = blockIdx.x * QT;
  int t = threadIdx.x;
  __shared__ float Qs[QT * 64];
  __shared__ float Ks[TKK * 65];
  __shared__ float4 Vs[TKK * 32];
  __shared__ float Ss[QT * 33];
  __shared__ float arow[QT], lrow[QT], lsn[TKK];
  const float* qp = ws + OQ + ((size_t)bh * Ll + q0) * 64;
  for (int i = t; i < QT * 64; i += 256) Qs[i] = qp[i];
  float m_r = -1e30f, l_r = 0.f;
  int rg = t >> 5, dvq = t & 31; int r0 = rg * 8;
  float4 Oa[8];
#pragma unroll
  for (int i = 0; i < 8; ++i) Oa[i] = make_float4(0.f, 0.f, 0.f, 0.f);
  int r = t >> 2, kb = (t & 3) * 8;
  for (int kt = 0; kt < Ll / TKK; ++kt) {
    int k0 = kt * TKK;
    const float* kp = ws + OK_ + ((size_t)bh * Ll + k0) * 64;
    for (int i = t; i < TKK * 64; i += 256) Ks[(i >> 6) * 65 + (i & 63)] = kp[i];
    const float4* vp = (const float4*)(ws + OV + ((size_t)bh * Ll + k0) * 128);
    for (int i = t; i < TKK * 32; i += 256) Vs[i] = vp[i];
    if (t < TKK) lsn[t] = logf(snr[b * Ll + k0 + t] + 1e-4f);
    __syncthreads();
    float acc[8];
#pragma unroll
    for (int i = 0; i < 8; ++i) acc[i] = 0.f;
    for (int d = 0; d < 64; ++d) {
      float qv = Qs[r * 64 + d];
#pragma unroll
      for (int i = 0; i < 8; ++i) acc[i] += qv * Ks[(kb + i) * 65 + d];
    }
#pragma unroll
    for (int i = 0; i < 8; ++i) Ss[r * 33 + kb + i] = acc[i] * 0.125f + lsn[kb + i];
    __syncthreads();
    if (t < QT) {
      float mx = m_r;
      for (int kk = 0; kk < TKK; ++kk) mx = fmaxf(mx, Ss[t * 33 + kk]);
      float al = __expf(m_r - mx);
      float s = 0.f;
      for (int kk = 0; kk < TKK; ++kk) {
        float p = __expf(Ss[t * 33 + kk] - mx);
        Ss[t * 33 + kk] = p; s += p;
      }
      l_r = l_r * al + s; m_r = mx; arow[t] = al;
    }
    __syncthreads();
#pragma unroll
    for (int ii = 0; ii < 8; ++ii) {
      float a = arow[r0 + ii];
      Oa[ii].x *= a; Oa[ii].y *= a; Oa[ii].z *= a; Oa[ii].w *= a;
    }
    for (int kk = 0; kk < TKK; ++kk) {
      float4 v4 = Vs[kk * 32 + dvq];
#pragma unroll
      for (int ii = 0; ii < 8; ++ii) {
        float p = Ss[(r0 + ii) * 33 + kk];
        Oa[ii].x += p * v4.x; Oa[ii].y += p * v4.y;
        Oa[ii].z += p * v4.z; Oa[ii].w += p * v4.w;
      }
    }
    __syncthreads();
  }
  if (t < QT) lrow[t] = l_r;
  __syncthreads();
  float* op = ws + OO + ((size_t)b * Ll + q0) * 1024 + hd * 128;
#pragma unroll
  for (int ii = 0; ii < 8; ++ii) {
    float inv = 1.f / lrow[r0 + ii];
    float4 o4 = make_float4(Oa[ii].x * inv, Oa[ii].y * inv,
                            Oa[ii].z * inv, Oa[ii].w * inv);
    *((float4*)(op + (size_t)(r0 + ii) * 1024) + dvq) = o4;
  }
}

// ============ 3. o@fc + residual + LN -> xh ============
__global__ __launch_bounds__(64) void k_oproj(const float* __restrict__ enc,
    const float* __restrict__ fc, const float* __restrict__ lnw,
    const float* __restrict__ lnb, float* __restrict__ ws) {
  int l = blockIdx.x, b = blockIdx.y, t = threadIdx.x;
  __shared__ float orow[1024];
  const float* op = ws + OO + ((size_t)b * Ll + l) * 1024;
  for (int i = t; i < 1024; i += 64) orow[i] = op[i];
  __syncthreads();
  float acc = 0.f;
#pragma unroll 4
  for (int j = 0; j < 1024; ++j) acc += orow[j] * fc[j * 64 + t];
  acc += enc[(size_t)b * Cc * Ll + (size_t)t * Ll + l];
  float s = acc;
#pragma unroll
  for (int o = 32; o >= 1; o >>= 1) s += __shfl_xor(s, o, 64);
  float m = s * (1.f / 64.f);
  float dd = acc - m;
  float vs = dd * dd;
#pragma unroll
  for (int o = 32; o >= 1; o >>= 1) vs += __shfl_xor(vs, o, 64);
  float var = vs * (1.f / 64.f);
  float y = dd * rsqrtf(var + 1e-5f) * lnw[t] + lnb[t];
  ws[OXH + ((size_t)b * Ll + l) * 64 + t] = y;
}

// ============ 4. xz = xh @ ss_in_w ============
__global__ __launch_bounds__(256) void k_xz(const float* __restrict__ ssin,
                                            float* __restrict__ ws) {
  int l = blockIdx.x, b = blockIdx.y, t = threadIdx.x;
  __shared__ float xr[64];
  if (t < 64) xr[t] = ws[OXH + ((size_t)b * Ll + l) * 64 + t];
  __syncthreads();
  float acc = 0.f;
#pragma unroll 8
  for (int c = 0; c < 64; ++c) acc += xr[c] * ssin[c * 256 + t];
  if (t < 128) ws[OX1P + ((size_t)b * Ll + l) * 128 + t] = acc;
  else ws[OZ + ((size_t)b * Ll + l) * 128 + (t - 128)] = acc;
}

// ============ 5. depthwise conv3x3 + bias + silu ============
__global__ __launch_bounds__(128) void k_conv(const float* __restrict__ cw,
    const float* __restrict__ cb, float* __restrict__ ws) {
  int l = blockIdx.x, b = blockIdx.y, d = threadIdx.x;
  int h = l / 48, w = l % 48;
  float acc = cb[d];
#pragma unroll
  for (int kh = 0; kh < 3; ++kh) {
    int hh = h + kh - 1;
    if (hh < 0 || hh >= 48) continue;
#pragma unroll
    for (int kw = 0; kw < 3; ++kw) {
      int wx = w + kw - 1;
      if (wx < 0 || wx >= 48) continue;
      acc += ws[OX1P + ((size_t)b * Ll + hh * 48 + wx) * 128 + d] *
             cw[d * 9 + kh * 3 + kw];
    }
  }
  ws[OX1S + ((size_t)b * Ll + l) * 128 + d] = siluf(acc);
}

// ============ 6. x_dbl projections -> dt2/Bs2/Cs2 (l-major) ============
__global__ __launch_bounds__(128) void k_xdbl(const float* __restrict__ xw,
    const float* __restrict__ dtw, const float* __restrict__ dtb,
    float* __restrict__ ws) {
  int l = blockIdx.x;
  int by = blockIdx.y; int b = by >> 2; int k = by & 3;
  int t = threadIdx.x;
  int sp = spmap(k, l);
  __shared__ float xv[128];
  __shared__ float pr[36];
  xv[t] = ws[OX1S + ((size_t)b * Ll + sp) * 128 + t];
  __syncthreads();
  if (t < 36) {
    float s = 0.f;
    const float* wp = xw + (size_t)(k * 36 + t) * 128;
#pragma unroll 8
    for (int d = 0; d < 128; ++d) s += xv[d] * wp[d];
    pr[t] = s;
  }
  __syncthreads();
  {
    int d = t;
    const float* wp = dtw + (size_t)(k * 128 + d) * 4;
    float v = pr[0] * wp[0] + pr[1] * wp[1] +
              pr[2] * wp[2] + pr[3] * wp[3] + dtb[k * 128 + d];
    ws[ODT2 + ((size_t)by * Ll + l) * 128 + d] = softplusf(v);
  }
  if (t < 16) ws[OBS2 + ((size_t)by * Ll + l) * 16 + t] = pr[4 + t];
  else if (t < 32) ws[OCS2 + ((size_t)by * Ll + l) * 16 + (t - 16)] = pr[20 + (t - 16)];
}

// ============ 7a. scan phase A: per-chunk transfer functions ============
__global__ __launch_bounds__(256) void k_scanA(const float* __restrict__ alog,
                                               float* __restrict__ ws) {
  int c = blockIdx.x;          // chunk
  int bk = blockIdx.y;         // b*4+k
  int b = bk >> 2, k = bk & 3;
  int t = threadIdx.x;
  int n = t & 15, dg = t >> 4;
  __shared__ float dt_s[128], x_s[128], Bs_s[16];
  float A_r[8], ap[8], bc[8];
#pragma unroll
  for (int i = 0; i < 8; ++i) {
    int d = dg * 8 + i;
    A_r[i] = -__expf(alog[(size_t)((k * 128 + d) * 16) + n]);
    ap[i] = 1.f; bc[i] = 0.f;
  }
  const float* dtp = ws + ODT2 + ((size_t)bk * Ll) * 128;
  const float* bsp = ws + OBS2 + ((size_t)bk * Ll) * 16;
  const float* xb = ws + OX1S + (size_t)b * Ll * 128;
  for (int ll = 0; ll < SCH; ++ll) {
    int l = c * SCH + ll;
    int sp = spmap(k, l);
    if (t < 128) dt_s[t] = dtp[(size_t)l * 128 + t];
    else x_s[t - 128] = xb[(size_t)sp * 128 + (t - 128)];
    if (t < 16) Bs_s[t] = bsp[(size_t)l * 16 + t];
    __syncthreads();
    float Bv = Bs_s[n];
#pragma unroll
    for (int i = 0; i < 8; ++i) {
      int d = dg * 8 + i;
      float dtv = dt_s[d];
      float a = __expf(dtv * A_r[i]);
      bc[i] = bc[i] * a + dtv * x_s[d] * Bv;
      ap[i] *= a;
    }
    __syncthreads();
  }
  float* csa = ws + OCSA + ((size_t)(bk * SNC + c) * 128) * 16;
  float* csb = ws + OCSB + ((size_t)(bk * SNC + c) * 128) * 16;
#pragma unroll
  for (int i = 0; i < 8; ++i) {
    int d = dg * 8 + i;
    csa[d * 16 + n] = ap[i];
    csb[d * 16 + n] = bc[i];
  }
}

// ============ 7b. scan phase B: compose chunk states ============
__global__ __launch_bounds__(256) void k_scanB(float* __restrict__ ws) {
  int g = blockIdx.x * 256 + threadIdx.x;   // 16384 recurrences
  int bk = g >> 11;
  int dn = g & 2047;
  const float* csa = ws + OCSA;
  const float* csb = ws + OCSB;
  float* hst = ws + OHST;
  float h = 0.f;
  for (int c = 0; c < SNC; ++c) {
    size_t idx = (size_t)(bk * SNC + c) * 2048 + dn;
    hst[idx] = h;
    h = csa[idx] * h + csb[idx];
  }
}

// ============ 7c. scan phase C: replay + emit y (l-major) ============
__global__ __launch_bounds__(256) void k_scanC(const float* __restrict__ alog,
    const float* __restrict__ Dp, float* __restrict__ ws) {
  int c = blockIdx.x, bk = blockIdx.y;
  int b = bk >> 2, k = bk & 3;
  int t = threadIdx.x;
  int n = t & 15, dg = t >> 4;
  __shared__ float dt_s[128], x_s[128], Bs_s[16], Cs_s[16];
  float A_r[8], h[8], Dv[8];
#pragma unroll
  for (int i = 0; i < 8; ++i) {
    int d = dg * 8 + i;
    A_r[i] = -__expf(alog[(size_t)((k * 128 + d) * 16) + n]);
    h[i] = ws[OHST + ((size_t)(bk * SNC + c) * 128 + d) * 16 + n];
    Dv[i] = Dp[k * 128 + d];
  }
  const float* dtp = ws + ODT2 + ((size_t)bk * Ll) * 128;
  const float* bsp = ws + OBS2 + ((size_t)bk * Ll) * 16;
  const float* csp = ws + OCS2 + ((size_t)bk * Ll) * 16;
  const float* xb = ws + OX1S + (size_t)b * Ll * 128;
  float* yp = ws + OYS2 + ((size_t)bk * Ll) * 128;
  for (int ll = 0; ll < SCH; ++ll) {
    int l = c * SCH + ll;
    int sp = spmap(k, l);
    if (t < 128) dt_s[t] = dtp[(size_t)l * 128 + t];
    else x_s[t - 128] = xb[(size_t)sp * 128 + (t - 128)];
    if (t < 16) Bs_s[t] = bsp[(size_t)l * 16 + t];
    else if (t < 32) Cs_s[t - 16] = csp[(size_t)l * 16 + (t - 16)];
    __syncthreads();
    float Bv = Bs_s[n], Cv = Cs_s[n];
    float yacc[8];
#pragma unroll
    for (int i = 0; i < 8; ++i) {
      int d = dg * 8 + i;
      float dtv = dt_s[d];
      float a = __expf(dtv * A_r[i]);
      h[i] = h[i] * a + dtv * x_s[d] * Bv;
      yacc[i] = h[i] * Cv;
    }
#pragma unroll
    for (int i = 0; i < 8; ++i) {
      float yv = yacc[i];
      yv += __shfl_xor(yv, 1, 64);
      yv += __shfl_xor(yv, 2, 64);
      yv += __shfl_xor(yv, 4, 64);
      yv += __shfl_xor(yv, 8, 64);
      yacc[i] = yv;
    }
    if (n == 0) {
#pragma unroll
      for (int i = 0; i < 8; ++i) {
        int d = dg * 8 + i;
        yp[(size_t)l * 128 + d] = yacc[i] + Dv[i] * x_s[d];
      }
    }
    __syncthreads();
  }
}

// ============ 8. combine dirs + LN + gate (l-major ys) ============
__global__ __launch_bounds__(128) void k_comb(const float* __restrict__ nw,
    const float* __restrict__ nb, const float* __restrict__ snr,
    float* __restrict__ ws) {
  int l = blockIdx.x, b = blockIdx.y, d = threadIdx.x;
  int h = l / 48, w = l % 48;
  int lT = w * 48 + h;
  const float* ysb = ws + OYS2;
  float v = ysb[((size_t)(b * 4 + 0) * Ll + l) * 128 + d] +
            ysb[((size_t)(b * 4 + 2) * Ll + (2303 - l)) * 128 + d] +
            ysb[((size_t)(b * 4 + 1) * Ll + lT) * 128 + d] +
            ysb[((size_t)(b * 4 + 3) * Ll + (2303 - lT)) * 128 + d];
  __shared__ float red[4];
  int lane = d & 63, wid = d >> 6;
  float s = v;
#pragma unroll
  for (int o = 32; o >= 1; o >>= 1) s += __shfl_xor(s, o, 64);
  if (lane == 0) red[wid] = s;
  __syncthreads();
  float m = (red[0] + red[1]) * (1.f / 128.f);
  float dv_ = v - m;
  float q = dv_ * dv_;
#pragma unroll
  for (int o = 32; o >= 1; o >>= 1) q += __shfl_xor(q, o, 64);
  if (lane == 0) red[wid + 2] = q;
  __syncthreads();
  float var = (red[2] + red[3]) * (1.f / 128.f);
  float y = dv_ * rsqrtf(var + 1e-5f) * nw[d] + nb[d];
  float zv = ws[OZ + ((size_t)b * Ll + l) * 128 + d];
  y *= siluf(zv);
  y *= snr[b * Ll + l];
  ws[OY2 + ((size_t)b * Ll + l) * 128 + d] = y;
}

// ============ 9. x2 = y2@out_w + enc residual; LN -> xn ============
__global__ __launch_bounds__(64) void k_outln(const float* __restrict__ enc,
    const float* __restrict__ ow, const float* __restrict__ lw,
    const float* __restrict__ lb, float* __restrict__ ws) {
  int l = blockIdx.x, b = blockIdx.y, c = threadIdx.x;
  __shared__ float yr[128];
  const float* yp = ws + OY2 + ((size_t)b * Ll + l) * 128;
  yr[c] = yp[c]; yr[c + 64] = yp[c + 64];
  __syncthreads();
  float acc = 0.f;
#pragma unroll 8
  for (int dd = 0; dd < 128; ++dd) acc += yr[dd] * ow[dd * 64 + c];
  acc += enc[(size_t)b * Cc * Ll + (size_t)c * Ll + l];
  ws[OX2 + ((size_t)b * Ll + l) * 64 + c] = acc;
  float s = acc;
#pragma unroll
  for (int o = 32; o >= 1; o >>= 1) s += __shfl_xor(s, o, 64);
  float m = s * (1.f / 64.f);
  float dd2 = acc - m;
  float vs = dd2 * dd2;
#pragma unroll
  for (int o = 32; o >= 1; o >>= 1) vs += __shfl_xor(vs, o, 64);
  float var = vs * (1.f / 64.f);
  float y = dd2 * rsqrtf(var + 1e-5f) * lw[c] + lb[c];
  ws[OXN + ((size_t)b * Ll + l) * 64 + c] = y;
}

// ============ 10. FFN conv1 1x1 + gelu ============
__global__ __launch_bounds__(256) void k_ffn1(const float* __restrict__ w1,
                                              float* __restrict__ ws) {
  int l = blockIdx.x, b = blockIdx.y, mch = threadIdx.x;
  __shared__ float xr[64];
  if (mch < 64) xr[mch] = ws[OXN + ((size_t)b * Ll + l) * 64 + mch];
  __syncthreads();
  float acc = 0.f;
  const float* wp = w1 + (size_t)mch * 64;
#pragma unroll 8
  for (int c = 0; c < 64; ++c) acc += xr[c] * wp[c];
  ws[OH1A + ((size_t)b * Ll + l) * 256 + mch] = geluf(acc);
}

// ============ 11. FFN depthwise 3x3 + gelu ============
__global__ __launch_bounds__(256) void k_ffndw(const float* __restrict__ dww,
                                               float* __restrict__ ws) {
  int l = blockIdx.x, b = blockIdx.y, mch = threadIdx.x;
  int h = l / 48, w = l % 48;
  float acc = 0.f;
#pragma unroll
  for (int kh = 0; kh < 3; ++kh) {
    int hh = h + kh - 1;
    if (hh < 0 || hh >= 48) continue;
#pragma unroll
    for (int kw = 0; kw < 3; ++kw) {
      int wx = w + kw - 1;
      if (wx < 0 || wx >= 48) continue;
      acc += ws[OH1A + ((size_t)b * Ll + hh * 48 + wx) * 256 + mch] *
             dww[mch * 9 + kh * 3 + kw];
    }
  }
  ws[OH1B + ((size_t)b * Ll + l) * 256 + mch] = geluf(acc);
}

// ============ 12. FFN conv2 1x1 + residual ============
__global__ __launch_bounds__(64) void k_ffn2(const float* __restrict__ w2,
                                             float* __restrict__ ws) {
  int l = blockIdx.x, b = blockIdx.y, c = threadIdx.x;
  __shared__ float hr[256];
  const float* hp = ws + OH1B + ((size_t)b * Ll + l) * 256;
  for (int i = c; i < 256; i += 64) hr[i] = hp[i];
  __syncthreads();
  float acc = 0.f;
  const float* wp = w2 + (size_t)c * 256;
#pragma unroll 8
  for (int mm = 0; mm < 256; ++mm) acc += hr[mm] * wp[mm];
  acc += ws[OX2 + ((size_t)b * Ll + l) * 64 + c];
  ws[OX3 + ((size_t)b * Ll + l) * 64 + c] = acc;
}

// ============ 13. transpose (B,L,C) -> (B,C,L) fp32 out ============
__global__ __launch_bounds__(256) void k_trout(const float* __restrict__ ws,
                                               float* __restrict__ out) {
  int b = blockIdx.y;
  int l0 = blockIdx.x * 64;
  int t = threadIdx.x;
  __shared__ float tile[64][65];
  const float* xp = ws + OX3 + ((size_t)b * Ll + l0) * 64;
  for (int i = t; i < 4096; i += 256) tile[i >> 6][i & 63] = xp[i];
  __syncthreads();
  for (int i = t; i < 4096; i += 256) {
    int c = i >> 6, li = i & 63;
    out[((size_t)(b * 64 + c)) * 2304 + l0 + li] = tile[li][c];
  }
}

extern "C" void kernel_launch(void* const* d_in, const int* in_sizes, int n_in,
                              void* d_out, int out_size, void* d_ws, size_t ws_size,
                              hipStream_t stream) {
  (void)in_sizes; (void)n_in; (void)out_size; (void)ws_size;
  const float* enc  = (const float*)d_in[0];
  const float* snr  = (const float*)d_in[1];
  const float* wq   = (const float*)d_in[2];
  const float* wk   = (const float*)d_in[3];
  const float* wv   = (const float*)d_in[4];
  const float* fc   = (const float*)d_in[5];
  const float* alnw = (const float*)d_in[6];
  const float* alnb = (const float*)d_in[7];
  const float* ssin = (const float*)d_in[8];
  const float* cw   = (const float*)d_in[9];
  const float* cb   = (const float*)d_in[10];
  const float* xw   = (const float*)d_in[11];
  const float* dtw  = (const float*)d_in[12];
  const float* dtb  = (const float*)d_in[13];
  const float* alog = (const float*)d_in[14];
  const float* Dp   = (const float*)d_in[15];
  const float* nw   = (const float*)d_in[16];
  const float* nb   = (const float*)d_in[17];
  const float* ow   = (const float*)d_in[18];
  const float* flnw = (const float*)d_in[19];
  const float* flnb = (const float*)d_in[20];
  const float* w1   = (const float*)d_in[21];
  const float* dww  = (const float*)d_in[22];
  const float* w2   = (const float*)d_in[23];
  float* ws = (float*)d_ws;
  float* out = (float*)d_out;

  hipLaunchKernelGGL(k_qkv, dim3(Bq * Ll), dim3(256), 0, stream, enc, wq, wk, wv, ws);
  hipLaunchKernelGGL(k_attn, dim3(Ll / QT, Bq * NHh), dim3(256), 0, stream, snr, ws);
  hipLaunchKernelGGL(k_oproj, dim3(Ll, Bq), dim3(64), 0, stream, enc, fc, alnw, alnb, ws);
  hipLaunchKernelGGL(k_xz, dim3(Ll, Bq), dim3(256), 0, stream, ssin, ws);
  hipLaunchKernelGGL(k_conv, dim3(Ll, Bq), dim3(128), 0, stream, cw, cb, ws);
  hipLaunchKernelGGL(k_xdbl, dim3(Ll, Bq * 4), dim3(128), 0, stream, xw, dtw, dtb, ws);
  hipLaunchKernelGGL(k_scanA, dim3(SNC, Bq * 4), dim3(256), 0, stream, alog, ws);
  hipLaunchKernelGGL(k_scanB, dim3(64), dim3(256), 0, stream, ws);
  hipLaunchKernelGGL(k_scanC, dim3(SNC, Bq * 4), dim3(256), 0, stream, alog, Dp, ws);
  hipLaunchKernelGGL(k_comb, dim3(Ll, Bq), dim3(128), 0, stream, nw, nb, snr, ws);
  hipLaunchKernelGGL(k_outln, dim3(Ll, Bq), dim3(64), 0, stream, enc, ow, flnw, flnb, ws);
  hipLaunchKernelGGL(k_ffn1, dim3(Ll, Bq), dim3(256), 0, stream, w1, ws);
  hipLaunchKernelGGL(k_ffndw, dim3(Ll, Bq), dim3(256), 0, stream, dww, ws);
  hipLaunchKernelGGL(k_ffn2, dim3(Ll, Bq), dim3(64), 0, stream, w2, ws);
  hipLaunchKernelGGL(k_trout, dim3(Ll / 64, Bq), dim3(256), 0, stream, ws, out);
}

// Round 7
// 747.216 us; speedup vs baseline: 3.4213x; 2.0464x over previous
//
#include <hip/hip_runtime.h>
#include <hip/hip_bf16.h>

#define Bq 2
#define Cc 64
#define Hh 48
#define Ww 48
#define Ll 2304
#define NHh 8
#define DKk 64
#define DVv 128
#define DNn 128
#define NSs 16
#define Rr 4
#define SCH 48   // scan chunk length
#define SNC 48   // number of chunks (SCH*SNC = Ll)

// ---- workspace layout (float offsets) ----
#define OQ    0u
#define OK_   2359296u
#define OV    4718592u
#define OO    9437184u
#define OXH   14155776u
#define OY2   14450688u
#define OX2   15040512u
#define OXN   15335424u
#define OVT   15630336u          // (B*8, 128, L) V transposed, 4718592 floats
#define WS_NEED_FLOATS (OVT + 4718592u)
// aliases (lifetimes: q,k,v,vt dead after k_attn; o dead after k_oproj)
#define ODT2  OQ                 // (B*4, L, 128) dt, l-major
#define OYS2  OK_                // (B*4, L, 128) scan y, l-major
#define OX1P  OV                 // (B,L,128)
#define OZ    (OV + 589824u)     // (B,L,128)
#define OX1S  (OV + 1179648u)    // (B,L,128)
#define OBS2  (OV + 1769472u)    // (B*4, L, 16)
#define OCS2  (OV + 2064384u)    // (B*4, L, 16)
#define OCSA  (OV + 2359296u)    // (B*4, SNC, 128, 16) chunk A-product
#define OCSB  (OV + 3145728u)    // (B*4, SNC, 128, 16) chunk B-composite
#define OHST  (OV + 3932160u)    // (B*4, SNC, 128, 16) chunk start state
#define OH1A  OO                 // (B,L,256)
#define OH1B  (OO + 1179648u)    // (B,L,256)
#define OX3   (OO + 2359296u)    // (B,L,64)

typedef short short8v __attribute__((ext_vector_type(8)));
typedef float f32x4 __attribute__((ext_vector_type(4)));

__device__ __forceinline__ float geluf(float x) {
  return 0.5f * x * (1.0f + erff(x * 0.70710678118654752f));
}
__device__ __forceinline__ float siluf(float x) {
  return x / (1.0f + __expf(-x));
}
__device__ __forceinline__ float softplusf(float x) {
  return fmaxf(x, 0.0f) + log1pf(__expf(-fabsf(x)));
}
__device__ __forceinline__ int spmap(int k, int l) {
  if (k == 0) return l;
  if (k == 1) return (l % 48) * 48 + l / 48;
  if (k == 2) return 2303 - l;
  int l2 = 2303 - l; return (l2 % 48) * 48 + l2 / 48;
}
__device__ __forceinline__ short f2bf(float f) {
  unsigned u = __float_as_uint(f);
  unsigned r = (u + 0x7FFFu + ((u >> 16) & 1u)) >> 16;
  return (short)r;
}

__global__ void k_code(float* out) { if (threadIdx.x == 0) out[0] = 25000.f; }

// ============ 1. QKV projection ============
__global__ __launch_bounds__(256) void k_qkv(const float* __restrict__ enc,
    const float* __restrict__ wq, const float* __restrict__ wk,
    const float* __restrict__ wv, float* __restrict__ ws) {
  int bl = blockIdx.x; int b = bl / Ll; int l = bl % Ll;
  int t = threadIdx.x;
  __shared__ float xr[64];
  if (t < 64) xr[t] = enc[(size_t)b * Cc * Ll + (size_t)t * Ll + l];
  __syncthreads();
  float* q = ws + OQ; float* k = ws + OK_; float* v = ws + OV;
#pragma unroll
  for (int i = 0; i < 8; ++i) {
    int j = t + i * 256;
    float acc = 0.f;
    if (j < 512) {
      const float* wp = wq; int col = j;
#pragma unroll 8
      for (int c = 0; c < 64; ++c) acc += xr[c] * wp[c * 512 + col];
      q[((size_t)(b * 8 + (col >> 6)) * Ll + l) * 64 + (col & 63)] = acc;
    } else if (j < 1024) {
      const float* wp = wk; int col = j - 512;
#pragma unroll 8
      for (int c = 0; c < 64; ++c) acc += xr[c] * wp[c * 512 + col];
      k[((size_t)(b * 8 + (col >> 6)) * Ll + l) * 64 + (col & 63)] = acc;
    } else {
      const float* wp = wv; int col = j - 1024;
#pragma unroll 8
      for (int c = 0; c < 64; ++c) acc += xr[c] * wp[c * 1024 + col];
      v[((size_t)(b * 8 + (col >> 7)) * Ll + l) * 128 + (col & 127)] = acc;
    }
  }
}

// ============ 1b. transpose V -> vt (bh, dv, L) ============
__global__ __launch_bounds__(256) void k_vt(float* __restrict__ ws) {
  int bh = blockIdx.y;
  int l0 = blockIdx.x * 64;
  int t = threadIdx.x;
  __shared__ float tile[128][65];
  const float* vp = ws + OV + ((size_t)bh * Ll + l0) * 128;
  for (int i = t; i < 64 * 32; i += 256) {
    int l = i >> 5, dv4 = (i & 31) * 4;
    float4 a = *(const float4*)(vp + (size_t)l * 128 + dv4);
    tile[dv4][l] = a.x; tile[dv4 + 1][l] = a.y;
    tile[dv4 + 2][l] = a.z; tile[dv4 + 3][l] = a.w;
  }
  __syncthreads();
  float* vt = ws + OVT + (size_t)bh * 128 * Ll + l0;
  for (int i = t; i < 128 * 16; i += 256) {
    int dv = i >> 4, l4 = (i & 15) * 4;
    float4 a = make_float4(tile[dv][l4], tile[dv][l4 + 1],
                           tile[dv][l4 + 2], tile[dv][l4 + 3]);
    *(float4*)(vt + (size_t)dv * Ll + l4) = a;
  }
}

// ============ 2. flash attention (bf16 MFMA) ============
#define ASK 72   // Ks row stride (ushort)
#define ASV 40   // Vs row stride (ushort)
#define ASP 40   // Ps row stride (ushort)
__global__ __launch_bounds__(256) void k_attn(const float* __restrict__ snr,
                                              float* __restrict__ ws) {
  int bh = blockIdx.y; int b = bh >> 3; int hd = bh & 7;
  int q0 = blockIdx.x * 64;
  int t = threadIdx.x;
  int w = t >> 6, lane = t & 63;
  int m16 = lane & 15, quad = lane >> 4;

  __shared__ __align__(16) unsigned short Ks[32 * ASK];     // [key][d]
  __shared__ __align__(16) unsigned short Vs[128 * ASV];    // [dv][key]
  __shared__ __align__(16) unsigned short Ps[4 * 16 * ASP]; // per-wave [qrow][key]
  __shared__ float lsn_s[32];
  __shared__ float asc[4][16];
  __shared__ float lsc[4][16];

  const float* qp = ws + OQ + ((size_t)bh * Ll) * 64;
  const float* kp = ws + OK_ + ((size_t)bh * Ll) * 64;
  const float* vtp = ws + OVT + ((size_t)bh * 128) * Ll;

  // Q A-fragments: rows q0+w*16+m16, k = s*32 + quad*8 + j
  short8v qa[2];
  {
    const float* qrp = qp + (size_t)(q0 + w * 16 + m16) * 64 + quad * 8;
#pragma unroll
    for (int s = 0; s < 2; ++s) {
      float4 a = *(const float4*)(qrp + s * 32);
      float4 c = *(const float4*)(qrp + s * 32 + 4);
      short8v f;
      f[0] = f2bf(a.x); f[1] = f2bf(a.y); f[2] = f2bf(a.z); f[3] = f2bf(a.w);
      f[4] = f2bf(c.x); f[5] = f2bf(c.y); f[6] = f2bf(c.z); f[7] = f2bf(c.w);
      qa[s] = f;
    }
  }
  f32x4 oacc[8];
#pragma unroll
  for (int i = 0; i < 8; ++i) oacc[i] = (f32x4)0.f;
  float m_r[4] = {-1e30f, -1e30f, -1e30f, -1e30f};
  float l_r[4] = {0.f, 0.f, 0.f, 0.f};

  for (int kt = 0; kt < Ll / 32; ++kt) {
    int k0 = kt * 32;
    __syncthreads();
    // stage K tile [32 keys][64 d] as bf16
    {
      int key = t >> 3, d0 = (t & 7) * 8;
      const float* src = kp + (size_t)(k0 + key) * 64 + d0;
      float4 a = *(const float4*)src;
      float4 c = *(const float4*)(src + 4);
      short tmp[8] = {f2bf(a.x), f2bf(a.y), f2bf(a.z), f2bf(a.w),
                      f2bf(c.x), f2bf(c.y), f2bf(c.z), f2bf(c.w)};
      *(short8v*)&Ks[key * ASK + d0] = *(short8v*)tmp;
    }
    // stage V^T tile [128 dv][32 keys] as bf16
    {
      int dv = t >> 1, key0 = (t & 1) * 16;
      const float* src = vtp + (size_t)dv * Ll + k0 + key0;
      short tmp[16];
#pragma unroll
      for (int i = 0; i < 4; ++i) {
        float4 a = *(const float4*)(src + i * 4);
        tmp[i * 4 + 0] = f2bf(a.x); tmp[i * 4 + 1] = f2bf(a.y);
        tmp[i * 4 + 2] = f2bf(a.z); tmp[i * 4 + 3] = f2bf(a.w);
      }
      *(short8v*)&Vs[dv * ASV + key0] = *(short8v*)&tmp[0];
      *(short8v*)&Vs[dv * ASV + key0 + 8] = *(short8v*)&tmp[8];
    }
    if (t < 32) lsn_s[t] = logf(snr[b * Ll + k0 + t] + 1e-4f);
    __syncthreads();

    // QK^T: S[qrow][key], 2 N-tiles of 16 keys
    f32x4 sac[2];
#pragma unroll
    for (int n = 0; n < 2; ++n) {
      int key = n * 16 + m16;
      short8v kb0 = *(const short8v*)&Ks[key * ASK + quad * 8];
      short8v kb1 = *(const short8v*)&Ks[key * ASK + 32 + quad * 8];
      f32x4 acc = (f32x4)0.f;
      acc = __builtin_amdgcn_mfma_f32_16x16x32_bf16(qa[0], kb0, acc, 0, 0, 0);
      acc = __builtin_amdgcn_mfma_f32_16x16x32_bf16(qa[1], kb1, acc, 0, 0, 0);
      sac[n] = acc;
    }
    float ls0 = lsn_s[m16], ls1 = lsn_s[16 + m16];
    float p0[4], p1[4], alpha[4];
#pragma unroll
    for (int r = 0; r < 4; ++r) {
      float s0 = sac[0][r] * 0.125f + ls0;
      float s1 = sac[1][r] * 0.125f + ls1;
      float mx = fmaxf(s0, s1);
      mx = fmaxf(mx, __shfl_xor(mx, 1, 64));
      mx = fmaxf(mx, __shfl_xor(mx, 2, 64));
      mx = fmaxf(mx, __shfl_xor(mx, 4, 64));
      mx = fmaxf(mx, __shfl_xor(mx, 8, 64));
      float nm = fmaxf(m_r[r], mx);
      alpha[r] = __expf(m_r[r] - nm);
      m_r[r] = nm;
      p0[r] = __expf(s0 - nm);
      p1[r] = __expf(s1 - nm);
      float rs = p0[r] + p1[r];
      rs += __shfl_xor(rs, 1, 64);
      rs += __shfl_xor(rs, 2, 64);
      rs += __shfl_xor(rs, 4, 64);
      rs += __shfl_xor(rs, 8, 64);
      l_r[r] = l_r[r] * alpha[r] + rs;
    }
    // publish alpha + P to per-wave LDS (same-wave RAW, no barrier needed)
    if (m16 == 0) {
#pragma unroll
      for (int r = 0; r < 4; ++r) asc[w][quad * 4 + r] = alpha[r];
    }
    unsigned short* pw = &Ps[w * 16 * ASP];
#pragma unroll
    for (int r = 0; r < 4; ++r) {
      pw[(quad * 4 + r) * ASP + m16] = (unsigned short)f2bf(p0[r]);
      pw[(quad * 4 + r) * ASP + 16 + m16] = (unsigned short)f2bf(p1[r]);
    }
    short8v pb = *(const short8v*)&pw[m16 * ASP + quad * 8];
    float av = asc[w][m16];
    // PV as O^T = V^T · P^T; rescale accs by alpha (col = qrow = lane&15)
#pragma unroll
    for (int dt_ = 0; dt_ < 8; ++dt_) {
      short8v va = *(const short8v*)&Vs[(dt_ * 16 + m16) * ASV + quad * 8];
      f32x4 o = oacc[dt_];
      o[0] *= av; o[1] *= av; o[2] *= av; o[3] *= av;
      oacc[dt_] = __builtin_amdgcn_mfma_f32_16x16x32_bf16(va, pb, o, 0, 0, 0);
    }
  }
  // epilogue: divide by l per qrow (= col = lane&15)
  if (m16 == 0) {
#pragma unroll
    for (int r = 0; r < 4; ++r) lsc[w][quad * 4 + r] = l_r[r];
  }
  float linv = 1.f / lsc[w][m16];
  float* op = ws + OO + ((size_t)(b * Ll + q0 + w * 16 + m16)) * 1024 + hd * 128;
#pragma unroll
  for (int dt_ = 0; dt_ < 8; ++dt_) {
#pragma unroll
    for (int r = 0; r < 4; ++r) {
      op[dt_ * 16 + quad * 4 + r] = oacc[dt_][r] * linv;
    }
  }
}

// ============ 3. o@fc + residual + LN -> xh ============
__global__ __launch_bounds__(64) void k_oproj(const float* __restrict__ enc,
    const float* __restrict__ fc, const float* __restrict__ lnw,
    const float* __restrict__ lnb, float* __restrict__ ws) {
  int l = blockIdx.x, b = blockIdx.y, t = threadIdx.x;
  __shared__ float orow[1024];
  const float* op = ws + OO + ((size_t)b * Ll + l) * 1024;
  for (int i = t; i < 1024; i += 64) orow[i] = op[i];
  __syncthreads();
  float acc = 0.f;
#pragma unroll 4
  for (int j = 0; j < 1024; ++j) acc += orow[j] * fc[j * 64 + t];
  acc += enc[(size_t)b * Cc * Ll + (size_t)t * Ll + l];
  float s = acc;
#pragma unroll
  for (int o = 32; o >= 1; o >>= 1) s += __shfl_xor(s, o, 64);
  float m = s * (1.f / 64.f);
  float dd = acc - m;
  float vs = dd * dd;
#pragma unroll
  for (int o = 32; o >= 1; o >>= 1) vs += __shfl_xor(vs, o, 64);
  float var = vs * (1.f / 64.f);
  float y = dd * rsqrtf(var + 1e-5f) * lnw[t] + lnb[t];
  ws[OXH + ((size_t)b * Ll + l) * 64 + t] = y;
}

// ============ 4. xz = xh @ ss_in_w ============
__global__ __launch_bounds__(256) void k_xz(const float* __restrict__ ssin,
                                            float* __restrict__ ws) {
  int l = blockIdx.x, b = blockIdx.y, t = threadIdx.x;
  __shared__ float xr[64];
  if (t < 64) xr[t] = ws[OXH + ((size_t)b * Ll + l) * 64 + t];
  __syncthreads();
  float acc = 0.f;
#pragma unroll 8
  for (int c = 0; c < 64; ++c) acc += xr[c] * ssin[c * 256 + t];
  if (t < 128) ws[OX1P + ((size_t)b * Ll + l) * 128 + t] = acc;
  else ws[OZ + ((size_t)b * Ll + l) * 128 + (t - 128)] = acc;
}

// ============ 5. depthwise conv3x3 + bias + silu ============
__global__ __launch_bounds__(128) void k_conv(const float* __restrict__ cw,
    const float* __restrict__ cb, float* __restrict__ ws) {
  int l = blockIdx.x, b = blockIdx.y, d = threadIdx.x;
  int h = l / 48, w = l % 48;
  float acc = cb[d];
#pragma unroll
  for (int kh = 0; kh < 3; ++kh) {
    int hh = h + kh - 1;
    if (hh < 0 || hh >= 48) continue;
#pragma unroll
    for (int kw = 0; kw < 3; ++kw) {
      int wx = w + kw - 1;
      if (wx < 0 || wx >= 48) continue;
      acc += ws[OX1P + ((size_t)b * Ll + hh * 48 + wx) * 128 + d] *
             cw[d * 9 + kh * 3 + kw];
    }
  }
  ws[OX1S + ((size_t)b * Ll + l) * 128 + d] = siluf(acc);
}

// ============ 6. x_dbl projections -> dt2/Bs2/Cs2 (l-major) ============
__global__ __launch_bounds__(128) void k_xdbl(const float* __restrict__ xw,
    const float* __restrict__ dtw, const float* __restrict__ dtb,
    float* __restrict__ ws) {
  int l = blockIdx.x;
  int by = blockIdx.y; int b = by >> 2; int k = by & 3;
  int t = threadIdx.x;
  int sp = spmap(k, l);
  __shared__ float xv[128];
  __shared__ float pr[36];
  xv[t] = ws[OX1S + ((size_t)b * Ll + sp) * 128 + t];
  __syncthreads();
  if (t < 36) {
    float s = 0.f;
    const float* wp = xw + (size_t)(k * 36 + t) * 128;
#pragma unroll 8
    for (int d = 0; d < 128; ++d) s += xv[d] * wp[d];
    pr[t] = s;
  }
  __syncthreads();
  {
    int d = t;
    const float* wp = dtw + (size_t)(k * 128 + d) * 4;
    float v = pr[0] * wp[0] + pr[1] * wp[1] +
              pr[2] * wp[2] + pr[3] * wp[3] + dtb[k * 128 + d];
    ws[ODT2 + ((size_t)by * Ll + l) * 128 + d] = softplusf(v);
  }
  if (t < 16) ws[OBS2 + ((size_t)by * Ll + l) * 16 + t] = pr[4 + t];
  else if (t < 32) ws[OCS2 + ((size_t)by * Ll + l) * 16 + (t - 16)] = pr[20 + (t - 16)];
}

// ============ 7a. scan phase A: per-chunk transfer functions ============
__global__ __launch_bounds__(256) void k_scanA(const float* __restrict__ alog,
                                               float* __restrict__ ws) {
  int c = blockIdx.x;
  int bk = blockIdx.y;
  int b = bk >> 2, k = bk & 3;
  int t = threadIdx.x;
  int n = t & 15, dg = t >> 4;
  __shared__ float dt_s[128], x_s[128], Bs_s[16];
  float A_r[8], ap[8], bc[8];
#pragma unroll
  for (int i = 0; i < 8; ++i) {
    int d = dg * 8 + i;
    A_r[i] = -__expf(alog[(size_t)((k * 128 + d) * 16) + n]);
    ap[i] = 1.f; bc[i] = 0.f;
  }
  const float* dtp = ws + ODT2 + ((size_t)bk * Ll) * 128;
  const float* bsp = ws + OBS2 + ((size_t)bk * Ll) * 16;
  const float* xb = ws + OX1S + (size_t)b * Ll * 128;
  for (int ll = 0; ll < SCH; ++ll) {
    int l = c * SCH + ll;
    int sp = spmap(k, l);
    if (t < 128) dt_s[t] = dtp[(size_t)l * 128 + t];
    else x_s[t - 128] = xb[(size_t)sp * 128 + (t - 128)];
    if (t < 16) Bs_s[t] = bsp[(size_t)l * 16 + t];
    __syncthreads();
    float Bv = Bs_s[n];
#pragma unroll
    for (int i = 0; i < 8; ++i) {
      int d = dg * 8 + i;
      float dtv = dt_s[d];
      float a = __expf(dtv * A_r[i]);
      bc[i] = bc[i] * a + dtv * x_s[d] * Bv;
      ap[i] *= a;
    }
    __syncthreads();
  }
  float* csa = ws + OCSA + ((size_t)(bk * SNC + c) * 128) * 16;
  float* csb = ws + OCSB + ((size_t)(bk * SNC + c) * 128) * 16;
#pragma unroll
  for (int i = 0; i < 8; ++i) {
    int d = dg * 8 + i;
    csa[d * 16 + n] = ap[i];
    csb[d * 16 + n] = bc[i];
  }
}

// ============ 7b. scan phase B: compose chunk states ============
__global__ __launch_bounds__(256) void k_scanB(float* __restrict__ ws) {
  int g = blockIdx.x * 256 + threadIdx.x;
  int bk = g >> 11;
  int dn = g & 2047;
  const float* csa = ws + OCSA;
  const float* csb = ws + OCSB;
  float* hst = ws + OHST;
  float h = 0.f;
  for (int c = 0; c < SNC; ++c) {
    size_t idx = (size_t)(bk * SNC + c) * 2048 + dn;
    hst[idx] = h;
    h = csa[idx] * h + csb[idx];
  }
}

// ============ 7c. scan phase C: replay + emit y (l-major) ============
__global__ __launch_bounds__(256) void k_scanC(const float* __restrict__ alog,
    const float* __restrict__ Dp, float* __restrict__ ws) {
  int c = blockIdx.x, bk = blockIdx.y;
  int b = bk >> 2, k = bk & 3;
  int t = threadIdx.x;
  int n = t & 15, dg = t >> 4;
  __shared__ float dt_s[128], x_s[128], Bs_s[16], Cs_s[16];
  float A_r[8], h[8], Dv[8];
#pragma unroll
  for (int i = 0; i < 8; ++i) {
    int d = dg * 8 + i;
    A_r[i] = -__expf(alog[(size_t)((k * 128 + d) * 16) + n]);
    h[i] = ws[OHST + ((size_t)(bk * SNC + c) * 128 + d) * 16 + n];
    Dv[i] = Dp[k * 128 + d];
  }
  const float* dtp = ws + ODT2 + ((size_t)bk * Ll) * 128;
  const float* bsp = ws + OBS2 + ((size_t)bk * Ll) * 16;
  const float* csp = ws + OCS2 + ((size_t)bk * Ll) * 16;
  const float* xb = ws + OX1S + (size_t)b * Ll * 128;
  float* yp = ws + OYS2 + ((size_t)bk * Ll) * 128;
  for (int ll = 0; ll < SCH; ++ll) {
    int l = c * SCH + ll;
    int sp = spmap(k, l);
    if (t < 128) dt_s[t] = dtp[(size_t)l * 128 + t];
    else x_s[t - 128] = xb[(size_t)sp * 128 + (t - 128)];
    if (t < 16) Bs_s[t] = bsp[(size_t)l * 16 + t];
    else if (t < 32) Cs_s[t - 16] = csp[(size_t)l * 16 + (t - 16)];
    __syncthreads();
    float Bv = Bs_s[n], Cv = Cs_s[n];
    float yacc[8];
#pragma unroll
    for (int i = 0; i < 8; ++i) {
      int d = dg * 8 + i;
      float dtv = dt_s[d];
      float a = __expf(dtv * A_r[i]);
      h[i] = h[i] * a + dtv * x_s[d] * Bv;
      yacc[i] = h[i] * Cv;
    }
#pragma unroll
    for (int i = 0; i < 8; ++i) {
      float yv = yacc[i];
      yv += __shfl_xor(yv, 1, 64);
      yv += __shfl_xor(yv, 2, 64);
      yv += __shfl_xor(yv, 4, 64);
      yv += __shfl_xor(yv, 8, 64);
      yacc[i] = yv;
    }
    if (n == 0) {
#pragma unroll
      for (int i = 0; i < 8; ++i) {
        int d = dg * 8 + i;
        yp[(size_t)l * 128 + d] = yacc[i] + Dv[i] * x_s[d];
      }
    }
    __syncthreads();
  }
}

// ============ 8. combine dirs + LN + gate (l-major ys) ============
__global__ __launch_bounds__(128) void k_comb(const float* __restrict__ nw,
    const float* __restrict__ nb, const float* __restrict__ snr,
    float* __restrict__ ws) {
  int l = blockIdx.x, b = blockIdx.y, d = threadIdx.x;
  int h = l / 48, w = l % 48;
  int lT = w * 48 + h;
  const float* ysb = ws + OYS2;
  float v = ysb[((size_t)(b * 4 + 0) * Ll + l) * 128 + d] +
            ysb[((size_t)(b * 4 + 2) * Ll + (2303 - l)) * 128 + d] +
            ysb[((size_t)(b * 4 + 1) * Ll + lT) * 128 + d] +
            ysb[((size_t)(b * 4 + 3) * Ll + (2303 - lT)) * 128 + d];
  __shared__ float red[4];
  int lane = d & 63, wid = d >> 6;
  float s = v;
#pragma unroll
  for (int o = 32; o >= 1; o >>= 1) s += __shfl_xor(s, o, 64);
  if (lane == 0) red[wid] = s;
  __syncthreads();
  float m = (red[0] + red[1]) * (1.f / 128.f);
  float dv_ = v - m;
  float q = dv_ * dv_;
#pragma unroll
  for (int o = 32; o >= 1; o >>= 1) q += __shfl_xor(q, o, 64);
  if (lane == 0) red[wid + 2] = q;
  __syncthreads();
  float var = (red[2] + red[3]) * (1.f / 128.f);
  float y = dv_ * rsqrtf(var + 1e-5f) * nw[d] + nb[d];
  float zv = ws[OZ + ((size_t)b * Ll + l) * 128 + d];
  y *= siluf(zv);
  y *= snr[b * Ll + l];
  ws[OY2 + ((size_t)b * Ll + l) * 128 + d] = y;
}

// ============ 9. x2 = y2@out_w + enc residual; LN -> xn ============
__global__ __launch_bounds__(64) void k_outln(const float* __restrict__ enc,
    const float* __restrict__ ow, const float* __restrict__ lw,
    const float* __restrict__ lb, float* __restrict__ ws) {
  int l = blockIdx.x, b = blockIdx.y, c = threadIdx.x;
  __shared__ float yr[128];
  const float* yp = ws + OY2 + ((size_t)b * Ll + l) * 128;
  yr[c] = yp[c]; yr[c + 64] = yp[c + 64];
  __syncthreads();
  float acc = 0.f;
#pragma unroll 8
  for (int dd = 0; dd < 128; ++dd) acc += yr[dd] * ow[dd * 64 + c];
  acc += enc[(size_t)b * Cc * Ll + (size_t)c * Ll + l];
  ws[OX2 + ((size_t)b * Ll + l) * 64 + c] = acc;
  float s = acc;
#pragma unroll
  for (int o = 32; o >= 1; o >>= 1) s += __shfl_xor(s, o, 64);
  float m = s * (1.f / 64.f);
  float dd2 = acc - m;
  float vs = dd2 * dd2;
#pragma unroll
  for (int o = 32; o >= 1; o >>= 1) vs += __shfl_xor(vs, o, 64);
  float var = vs * (1.f / 64.f);
  float y = dd2 * rsqrtf(var + 1e-5f) * lw[c] + lb[c];
  ws[OXN + ((size_t)b * Ll + l) * 64 + c] = y;
}

// ============ 10. FFN conv1 1x1 + gelu ============
__global__ __launch_bounds__(256) void k_ffn1(const float* __restrict__ w1,
                                              float* __restrict__ ws) {
  int l = blockIdx.x, b = blockIdx.y, mch = threadIdx.x;
  __shared__ float xr[64];
  if (mch < 64) xr[mch] = ws[OXN + ((size_t)b * Ll + l) * 64 + mch];
  __syncthreads();
  float acc = 0.f;
  const float* wp = w1 + (size_t)mch * 64;
#pragma unroll 8
  for (int c = 0; c < 64; ++c) acc += xr[c] * wp[c];
  ws[OH1A + ((size_t)b * Ll + l) * 256 + mch] = geluf(acc);
}

// ============ 11. FFN depthwise 3x3 + gelu ============
__global__ __launch_bounds__(256) void k_ffndw(const float* __restrict__ dww,
                                               float* __restrict__ ws) {
  int l = blockIdx.x, b = blockIdx.y, mch = threadIdx.x;
  int h = l / 48, w = l % 48;
  float acc = 0.f;
#pragma unroll
  for (int kh = 0; kh < 3; ++kh) {
    int hh = h + kh - 1;
    if (hh < 0 || hh >= 48) continue;
#pragma unroll
    for (int kw = 0; kw < 3; ++kw) {
      int wx = w + kw - 1;
      if (wx < 0 || wx >= 48) continue;
      acc += ws[OH1A + ((size_t)b * Ll + hh * 48 + wx) * 256 + mch] *
             dww[mch * 9 + kh * 3 + kw];
    }
  }
  ws[OH1B + ((size_t)b * Ll + l) * 256 + mch] = geluf(acc);
}

// ============ 12. FFN conv2 1x1 + residual ============
__global__ __launch_bounds__(64) void k_ffn2(const float* __restrict__ w2,
                                             float* __restrict__ ws) {
  int l = blockIdx.x, b = blockIdx.y, c = threadIdx.x;
  __shared__ float hr[256];
  const float* hp = ws + OH1B + ((size_t)b * Ll + l) * 256;
  for (int i = c; i < 256; i += 64) hr[i] = hp[i];
  __syncthreads();
  float acc = 0.f;
  const float* wp = w2 + (size_t)c * 256;
#pragma unroll 8
  for (int mm = 0; mm < 256; ++mm) acc += hr[mm] * wp[mm];
  acc += ws[OX2 + ((size_t)b * Ll + l) * 64 + c];
  ws[OX3 + ((size_t)b * Ll + l) * 64 + c] = acc;
}

// ============ 13. transpose (B,L,C) -> (B,C,L) fp32 out ============
__global__ __launch_bounds__(256) void k_trout(const float* __restrict__ ws,
                                               float* __restrict__ out) {
  int b = blockIdx.y;
  int l0 = blockIdx.x * 64;
  int t = threadIdx.x;
  __shared__ float tile[64][65];
  const float* xp = ws + OX3 + ((size_t)b * Ll + l0) * 64;
  for (int i = t; i < 4096; i += 256) tile[i >> 6][i & 63] = xp[i];
  __syncthreads();
  for (int i = t; i < 4096; i += 256) {
    int c = i >> 6, li = i & 63;
    out[((size_t)(b * 64 + c)) * 2304 + l0 + li] = tile[li][c];
  }
}

extern "C" void kernel_launch(void* const* d_in, const int* in_sizes, int n_in,
                              void* d_out, int out_size, void* d_ws, size_t ws_size,
                              hipStream_t stream) {
  (void)in_sizes; (void)n_in; (void)out_size;
  const float* enc  = (const float*)d_in[0];
  const float* snr  = (const float*)d_in[1];
  const float* wq   = (const float*)d_in[2];
  const float* wk   = (const float*)d_in[3];
  const float* wv   = (const float*)d_in[4];
  const float* fc   = (const float*)d_in[5];
  const float* alnw = (const float*)d_in[6];
  const float* alnb = (const float*)d_in[7];
  const float* ssin = (const float*)d_in[8];
  const float* cw   = (const float*)d_in[9];
  const float* cb   = (const float*)d_in[10];
  const float* xw   = (const float*)d_in[11];
  const float* dtw  = (const float*)d_in[12];
  const float* dtb  = (const float*)d_in[13];
  const float* alog = (const float*)d_in[14];
  const float* Dp   = (const float*)d_in[15];
  const float* nw   = (const float*)d_in[16];
  const float* nb   = (const float*)d_in[17];
  const float* ow   = (const float*)d_in[18];
  const float* flnw = (const float*)d_in[19];
  const float* flnb = (const float*)d_in[20];
  const float* w1   = (const float*)d_in[21];
  const float* dww  = (const float*)d_in[22];
  const float* w2   = (const float*)d_in[23];
  float* ws = (float*)d_ws;
  float* out = (float*)d_out;

  if (ws_size < (size_t)WS_NEED_FLOATS * 4) {
    hipLaunchKernelGGL(k_code, dim3(1), dim3(64), 0, stream, out);
    return;
  }

  hipLaunchKernelGGL(k_qkv, dim3(Bq * Ll), dim3(256), 0, stream, enc, wq, wk, wv, ws);
  hipLaunchKernelGGL(k_vt, dim3(Ll / 64, Bq * NHh), dim3(256), 0, stream, ws);
  hipLaunchKernelGGL(k_attn, dim3(Ll / 64, Bq * NHh), dim3(256), 0, stream, snr, ws);
  hipLaunchKernelGGL(k_oproj, dim3(Ll, Bq), dim3(64), 0, stream, enc, fc, alnw, alnb, ws);
  hipLaunchKernelGGL(k_xz, dim3(Ll, Bq), dim3(256), 0, stream, ssin, ws);
  hipLaunchKernelGGL(k_conv, dim3(Ll, Bq), dim3(128), 0, stream, cw, cb, ws);
  hipLaunchKernelGGL(k_xdbl, dim3(Ll, Bq * 4), dim3(128), 0, stream, xw, dtw, dtb, ws);
  hipLaunchKernelGGL(k_scanA, dim3(SNC, Bq * 4), dim3(256), 0, stream, alog, ws);
  hipLaunchKernelGGL(k_scanB, dim3(64), dim3(256), 0, stream, ws);
  hipLaunchKernelGGL(k_scanC, dim3(SNC, Bq * 4), dim3(256), 0, stream, alog, Dp, ws);
  hipLaunchKernelGGL(k_comb, dim3(Ll, Bq), dim3(128), 0, stream, nw, nb, snr, ws);
  hipLaunchKernelGGL(k_outln, dim3(Ll, Bq), dim3(64), 0, stream, enc, ow, flnw, flnb, ws);
  hipLaunchKernelGGL(k_ffn1, dim3(Ll, Bq), dim3(256), 0, stream, w1, ws);
  hipLaunchKernelGGL(k_ffndw, dim3(Ll, Bq), dim3(256), 0, stream, dww, ws);
  hipLaunchKernelGGL(k_ffn2, dim3(Ll, Bq), dim3(64), 0, stream, w2, ws);
  hipLaunchKernelGGL(k_trout, dim3(Ll / 64, Bq), dim3(256), 0, stream, ws, out);
}

// Round 8
// 691.846 us; speedup vs baseline: 3.6951x; 1.0800x over previous
//
#include <hip/hip_runtime.h>
#include <hip/hip_bf16.h>

#define Bq 2
#define Cc 64
#define Hh 48
#define Ww 48
#define Ll 2304
#define NHh 8
#define DKk 64
#define DVv 128
#define DNn 128
#define NSs 16
#define Rr 4
#define SCH 48
#define SNC 48

// ---- workspace layout (float offsets) ----
#define OQ    0u                 // (B*8, L, 64) Q bf16 (ushort)
#define OK_   2359296u           // (B*8, L, 64) K bf16 (ushort)
#define OV    4718592u           // (B*8, L, 128) V fp32
#define OO    9437184u           // (B, L, 1024) attention out fp32
#define OXH   14155776u          // (unused now, kept for offsets)
#define OY2   14450688u
#define OX2   15040512u
#define OXN   15335424u
#define OVT   15630336u          // (B*8, 128, L) V^T bf16 (ushort)
#define WS_NEED_FLOATS (OVT + 4718592u)
// aliases (lifetimes: q,k,v,vt dead after k_attn; o dead after k_oprojxz)
#define ODT2  OQ                 // (B*4, L, 128) dt, l-major
#define OYS2  OK_                // (B*4, L, 128) scan y, l-major
#define OX1P  OV                 // (B,L,128)
#define OZ    (OV + 589824u)     // (B,L,128)
#define OX1S  (OV + 1179648u)    // (B,L,128)
#define OBS2  (OV + 1769472u)    // (B*4, L, 16)
#define OCS2  (OV + 2064384u)    // (B*4, L, 16)
#define OCSA  (OV + 2359296u)    // (B*4, SNC, 128, 16)
#define OCSB  (OV + 3145728u)    // (B*4, SNC, 128, 16)
#define OHST  (OV + 3932160u)    // (B*4, SNC, 128, 16)
#define OH1A  OO                 // (B,L,256)
#define OH1B  (OO + 1179648u)    // (B,L,256)
#define OX3   (OO + 2359296u)    // (B,L,64)

typedef short short8v __attribute__((ext_vector_type(8)));
typedef short short4v __attribute__((ext_vector_type(4)));
typedef float f32x4 __attribute__((ext_vector_type(4)));
typedef unsigned short ushort_t;

__device__ __forceinline__ float geluf(float x) {
  return 0.5f * x * (1.0f + erff(x * 0.70710678118654752f));
}
__device__ __forceinline__ float siluf(float x) {
  return x / (1.0f + __expf(-x));
}
__device__ __forceinline__ float softplusf(float x) {
  return fmaxf(x, 0.0f) + log1pf(__expf(-fabsf(x)));
}
__device__ __forceinline__ int spmap(int k, int l) {
  if (k == 0) return l;
  if (k == 1) return (l % 48) * 48 + l / 48;
  if (k == 2) return 2303 - l;
  int l2 = 2303 - l; return (l2 % 48) * 48 + l2 / 48;
}
__device__ __forceinline__ short f2bf(float f) {
  unsigned u = __float_as_uint(f);
  unsigned r = (u + 0x7FFFu + ((u >> 16) & 1u)) >> 16;
  return (short)r;
}

__global__ void k_code(float* out) { if (threadIdx.x == 0) out[0] = 25000.f; }

// ============ 1. QKV projection (Q,K stored bf16; V fp32) ============
__global__ __launch_bounds__(256) void k_qkv(const float* __restrict__ enc,
    const float* __restrict__ wq, const float* __restrict__ wk,
    const float* __restrict__ wv, float* __restrict__ ws) {
  int bl = blockIdx.x; int b = bl / Ll; int l = bl % Ll;
  int t = threadIdx.x;
  __shared__ float xr[64];
  if (t < 64) xr[t] = enc[(size_t)b * Cc * Ll + (size_t)t * Ll + l];
  __syncthreads();
  ushort_t* qb = (ushort_t*)(ws + OQ);
  ushort_t* kb = (ushort_t*)(ws + OK_);
  float* v = ws + OV;
#pragma unroll
  for (int i = 0; i < 8; ++i) {
    int j = t + i * 256;
    float acc = 0.f;
    if (j < 512) {
      const float* wp = wq; int col = j;
#pragma unroll 8
      for (int c = 0; c < 64; ++c) acc += xr[c] * wp[c * 512 + col];
      qb[((size_t)(b * 8 + (col >> 6)) * Ll + l) * 64 + (col & 63)] = (ushort_t)f2bf(acc);
    } else if (j < 1024) {
      const float* wp = wk; int col = j - 512;
#pragma unroll 8
      for (int c = 0; c < 64; ++c) acc += xr[c] * wp[c * 512 + col];
      kb[((size_t)(b * 8 + (col >> 6)) * Ll + l) * 64 + (col & 63)] = (ushort_t)f2bf(acc);
    } else {
      const float* wp = wv; int col = j - 1024;
#pragma unroll 8
      for (int c = 0; c < 64; ++c) acc += xr[c] * wp[c * 1024 + col];
      v[((size_t)(b * 8 + (col >> 7)) * Ll + l) * 128 + (col & 127)] = acc;
    }
  }
}

// ============ 1b. transpose V -> vt bf16 (bh, dv, L) ============
__global__ __launch_bounds__(256) void k_vt(float* __restrict__ ws) {
  int bh = blockIdx.y;
  int l0 = blockIdx.x * 64;
  int t = threadIdx.x;
  __shared__ float tile[128][65];
  const float* vp = ws + OV + ((size_t)bh * Ll + l0) * 128;
  for (int i = t; i < 64 * 32; i += 256) {
    int l = i >> 5, dv4 = (i & 31) * 4;
    float4 a = *(const float4*)(vp + (size_t)l * 128 + dv4);
    tile[dv4][l] = a.x; tile[dv4 + 1][l] = a.y;
    tile[dv4 + 2][l] = a.z; tile[dv4 + 3][l] = a.w;
  }
  __syncthreads();
  ushort_t* vt = (ushort_t*)(ws + OVT) + (size_t)bh * 128 * Ll + l0;
  for (int i = t; i < 128 * 16; i += 256) {
    int dv = i >> 4, l4 = (i & 15) * 4;
    short4v a;
    a[0] = f2bf(tile[dv][l4]); a[1] = f2bf(tile[dv][l4 + 1]);
    a[2] = f2bf(tile[dv][l4 + 2]); a[3] = f2bf(tile[dv][l4 + 3]);
    *(short4v*)(vt + (size_t)dv * Ll + l4) = a;
  }
}

// ============ 2. flash attention (bf16 MFMA, bf16 staging) ============
#define ASK 72   // Ks row stride (ushort)
#define ASV 40   // Vs row stride (ushort)
#define ASP 40   // Ps row stride (ushort)
__global__ __launch_bounds__(256) void k_attn(const float* __restrict__ snr,
                                              float* __restrict__ ws) {
  int bh = blockIdx.y; int b = bh >> 3; int hd = bh & 7;
  int q0 = blockIdx.x * 64;
  int t = threadIdx.x;
  int w = t >> 6, lane = t & 63;
  int m16 = lane & 15, quad = lane >> 4;

  __shared__ __align__(16) ushort_t Ks[32 * ASK];     // [key][d]
  __shared__ __align__(16) ushort_t Vs[128 * ASV];    // [dv][key]
  __shared__ __align__(16) ushort_t Ps[4 * 16 * ASP]; // per-wave [qrow][key]
  __shared__ float lsn_s[32];
  __shared__ float asc[4][16];
  __shared__ float lsc[4][16];

  const ushort_t* qbf = (const ushort_t*)(ws + OQ) + (size_t)bh * Ll * 64;
  const ushort_t* kbf = (const ushort_t*)(ws + OK_) + (size_t)bh * Ll * 64;
  const ushort_t* vtb = (const ushort_t*)(ws + OVT) + (size_t)bh * 128 * Ll;

  short8v qa[2];
  {
    const ushort_t* qrp = qbf + (size_t)(q0 + w * 16 + m16) * 64 + quad * 8;
    qa[0] = *(const short8v*)qrp;
    qa[1] = *(const short8v*)(qrp + 32);
  }
  f32x4 oacc[8];
#pragma unroll
  for (int i = 0; i < 8; ++i) oacc[i] = (f32x4)0.f;
  float m_r[4] = {-1e30f, -1e30f, -1e30f, -1e30f};
  float l_r[4] = {0.f, 0.f, 0.f, 0.f};

  for (int kt = 0; kt < Ll / 32; ++kt) {
    int k0 = kt * 32;
    __syncthreads();
    // stage K tile [32 keys][64 d]: pure 16B copies
    {
      int key = t >> 3, d0 = (t & 7) * 8;
      *(short8v*)&Ks[key * ASK + d0] =
          *(const short8v*)(kbf + (size_t)(k0 + key) * 64 + d0);
    }
    // stage V^T tile [128 dv][32 keys]: two 16B copies
    {
      int dv = t >> 1, key0 = (t & 1) * 16;
      const ushort_t* src = vtb + (size_t)dv * Ll + k0 + key0;
      *(short8v*)&Vs[dv * ASV + key0] = *(const short8v*)src;
      *(short8v*)&Vs[dv * ASV + key0 + 8] = *(const short8v*)(src + 8);
    }
    if (t < 32) lsn_s[t] = logf(snr[b * Ll + k0 + t] + 1e-4f);
    __syncthreads();

    f32x4 sac[2];
#pragma unroll
    for (int n = 0; n < 2; ++n) {
      int key = n * 16 + m16;
      short8v kb0 = *(const short8v*)&Ks[key * ASK + quad * 8];
      short8v kb1 = *(const short8v*)&Ks[key * ASK + 32 + quad * 8];
      f32x4 acc = (f32x4)0.f;
      acc = __builtin_amdgcn_mfma_f32_16x16x32_bf16(qa[0], kb0, acc, 0, 0, 0);
      acc = __builtin_amdgcn_mfma_f32_16x16x32_bf16(qa[1], kb1, acc, 0, 0, 0);
      sac[n] = acc;
    }
    float ls0 = lsn_s[m16], ls1 = lsn_s[16 + m16];
    float p0[4], p1[4], alpha[4];
#pragma unroll
    for (int r = 0; r < 4; ++r) {
      float s0 = sac[0][r] * 0.125f + ls0;
      float s1 = sac[1][r] * 0.125f + ls1;
      float mx = fmaxf(s0, s1);
      mx = fmaxf(mx, __shfl_xor(mx, 1, 64));
      mx = fmaxf(mx, __shfl_xor(mx, 2, 64));
      mx = fmaxf(mx, __shfl_xor(mx, 4, 64));
      mx = fmaxf(mx, __shfl_xor(mx, 8, 64));
      float nm = fmaxf(m_r[r], mx);
      alpha[r] = __expf(m_r[r] - nm);
      m_r[r] = nm;
      p0[r] = __expf(s0 - nm);
      p1[r] = __expf(s1 - nm);
      float rs = p0[r] + p1[r];
      rs += __shfl_xor(rs, 1, 64);
      rs += __shfl_xor(rs, 2, 64);
      rs += __shfl_xor(rs, 4, 64);
      rs += __shfl_xor(rs, 8, 64);
      l_r[r] = l_r[r] * alpha[r] + rs;
    }
    if (m16 == 0) {
#pragma unroll
      for (int r = 0; r < 4; ++r) asc[w][quad * 4 + r] = alpha[r];
    }
    ushort_t* pw = &Ps[w * 16 * ASP];
#pragma unroll
    for (int r = 0; r < 4; ++r) {
      pw[(quad * 4 + r) * ASP + m16] = (ushort_t)f2bf(p0[r]);
      pw[(quad * 4 + r) * ASP + 16 + m16] = (ushort_t)f2bf(p1[r]);
    }
    short8v pb = *(const short8v*)&pw[m16 * ASP + quad * 8];
    float av = asc[w][m16];
#pragma unroll
    for (int dt_ = 0; dt_ < 8; ++dt_) {
      short8v va = *(const short8v*)&Vs[(dt_ * 16 + m16) * ASV + quad * 8];
      f32x4 o = oacc[dt_];
      o[0] *= av; o[1] *= av; o[2] *= av; o[3] *= av;
      oacc[dt_] = __builtin_amdgcn_mfma_f32_16x16x32_bf16(va, pb, o, 0, 0, 0);
    }
  }
  if (m16 == 0) {
#pragma unroll
    for (int r = 0; r < 4; ++r) lsc[w][quad * 4 + r] = l_r[r];
  }
  float linv = 1.f / lsc[w][m16];
  float* op = ws + OO + ((size_t)(b * Ll + q0 + w * 16 + m16)) * 1024 + hd * 128;
#pragma unroll
  for (int dt_ = 0; dt_ < 8; ++dt_) {
#pragma unroll
    for (int r = 0; r < 4; ++r) {
      op[dt_ * 16 + quad * 4 + r] = oacc[dt_][r] * linv;
    }
  }
}

// ============ 3+4. o@fc + residual + LN + xz projection (fused) ============
__global__ __launch_bounds__(256) void k_oprojxz(const float* __restrict__ enc,
    const float* __restrict__ fc, const float* __restrict__ lnw,
    const float* __restrict__ lnb, const float* __restrict__ ssin,
    float* __restrict__ ws) {
  int l = blockIdx.x, b = blockIdx.y, t = threadIdx.x;
  __shared__ float orow[1024];
  __shared__ float part[4][64];
  __shared__ float xh_s[64];
  const float* op = ws + OO + ((size_t)b * Ll + l) * 1024;
#pragma unroll
  for (int i = 0; i < 4; ++i) orow[t + i * 256] = op[t + i * 256];
  __syncthreads();
  int col = t & 63, seg = t >> 6;
  {
    float p = 0.f;
    const float* fcs = fc + (size_t)(seg * 256) * 64 + col;
#pragma unroll 8
    for (int j = 0; j < 256; ++j) p += orow[seg * 256 + j] * fcs[j * 64];
    part[seg][col] = p;
  }
  __syncthreads();
  if (t < 64) {
    float acc = part[0][t] + part[1][t] + part[2][t] + part[3][t];
    acc += enc[(size_t)b * Cc * Ll + (size_t)t * Ll + l];
    float s = acc;
#pragma unroll
    for (int o = 32; o >= 1; o >>= 1) s += __shfl_xor(s, o, 64);
    float m = s * (1.f / 64.f);
    float dd = acc - m;
    float vs = dd * dd;
#pragma unroll
    for (int o = 32; o >= 1; o >>= 1) vs += __shfl_xor(vs, o, 64);
    float var = vs * (1.f / 64.f);
    xh_s[t] = dd * rsqrtf(var + 1e-5f) * lnw[t] + lnb[t];
  }
  __syncthreads();
  float acc2 = 0.f;
#pragma unroll 8
  for (int c = 0; c < 64; ++c) acc2 += xh_s[c] * ssin[c * 256 + t];
  if (t < 128) ws[OX1P + ((size_t)b * Ll + l) * 128 + t] = acc2;
  else ws[OZ + ((size_t)b * Ll + l) * 128 + (t - 128)] = acc2;
}

// ============ 5. depthwise conv3x3 + bias + silu ============
__global__ __launch_bounds__(128) void k_conv(const float* __restrict__ cw,
    const float* __restrict__ cb, float* __restrict__ ws) {
  int l = blockIdx.x, b = blockIdx.y, d = threadIdx.x;
  int h = l / 48, w = l % 48;
  float acc = cb[d];
#pragma unroll
  for (int kh = 0; kh < 3; ++kh) {
    int hh = h + kh - 1;
    if (hh < 0 || hh >= 48) continue;
#pragma unroll
    for (int kw = 0; kw < 3; ++kw) {
      int wx = w + kw - 1;
      if (wx < 0 || wx >= 48) continue;
      acc += ws[OX1P + ((size_t)b * Ll + hh * 48 + wx) * 128 + d] *
             cw[d * 9 + kh * 3 + kw];
    }
  }
  ws[OX1S + ((size_t)b * Ll + l) * 128 + d] = siluf(acc);
}

// ============ 6. x_dbl projections -> dt2/Bs2/Cs2 (l-major) ============
__global__ __launch_bounds__(128) void k_xdbl(const float* __restrict__ xw,
    const float* __restrict__ dtw, const float* __restrict__ dtb,
    float* __restrict__ ws) {
  int l = blockIdx.x;
  int by = blockIdx.y; int b = by >> 2; int k = by & 3;
  int t = threadIdx.x;
  int sp = spmap(k, l);
  __shared__ float xv[128];
  __shared__ float pr[36];
  xv[t] = ws[OX1S + ((size_t)b * Ll + sp) * 128 + t];
  __syncthreads();
  if (t < 36) {
    float s = 0.f;
    const float* wp = xw + (size_t)(k * 36 + t) * 128;
#pragma unroll 8
    for (int d = 0; d < 128; ++d) s += xv[d] * wp[d];
    pr[t] = s;
  }
  __syncthreads();
  {
    int d = t;
    const float* wp = dtw + (size_t)(k * 128 + d) * 4;
    float v = pr[0] * wp[0] + pr[1] * wp[1] +
              pr[2] * wp[2] + pr[3] * wp[3] + dtb[k * 128 + d];
    ws[ODT2 + ((size_t)by * Ll + l) * 128 + d] = softplusf(v);
  }
  if (t < 16) ws[OBS2 + ((size_t)by * Ll + l) * 16 + t] = pr[4 + t];
  else if (t < 32) ws[OCS2 + ((size_t)by * Ll + l) * 16 + (t - 16)] = pr[20 + (t - 16)];
}

// ============ 7a. scan phase A ============
__global__ __launch_bounds__(256) void k_scanA(const float* __restrict__ alog,
                                               float* __restrict__ ws) {
  int c = blockIdx.x;
  int bk = blockIdx.y;
  int b = bk >> 2, k = bk & 3;
  int t = threadIdx.x;
  int n = t & 15, dg = t >> 4;
  __shared__ float dt_s[128], x_s[128], Bs_s[16];
  float A_r[8], ap[8], bc[8];
#pragma unroll
  for (int i = 0; i < 8; ++i) {
    int d = dg * 8 + i;
    A_r[i] = -__expf(alog[(size_t)((k * 128 + d) * 16) + n]);
    ap[i] = 1.f; bc[i] = 0.f;
  }
  const float* dtp = ws + ODT2 + ((size_t)bk * Ll) * 128;
  const float* bsp = ws + OBS2 + ((size_t)bk * Ll) * 16;
  const float* xb = ws + OX1S + (size_t)b * Ll * 128;
  for (int ll = 0; ll < SCH; ++ll) {
    int l = c * SCH + ll;
    int sp = spmap(k, l);
    if (t < 128) dt_s[t] = dtp[(size_t)l * 128 + t];
    else x_s[t - 128] = xb[(size_t)sp * 128 + (t - 128)];
    if (t < 16) Bs_s[t] = bsp[(size_t)l * 16 + t];
    __syncthreads();
    float Bv = Bs_s[n];
#pragma unroll
    for (int i = 0; i < 8; ++i) {
      int d = dg * 8 + i;
      float dtv = dt_s[d];
      float a = __expf(dtv * A_r[i]);
      bc[i] = bc[i] * a + dtv * x_s[d] * Bv;
      ap[i] *= a;
    }
    __syncthreads();
  }
  float* csa = ws + OCSA + ((size_t)(bk * SNC + c) * 128) * 16;
  float* csb = ws + OCSB + ((size_t)(bk * SNC + c) * 128) * 16;
#pragma unroll
  for (int i = 0; i < 8; ++i) {
    int d = dg * 8 + i;
    csa[d * 16 + n] = ap[i];
    csb[d * 16 + n] = bc[i];
  }
}

// ============ 7b. scan phase B ============
__global__ __launch_bounds__(256) void k_scanB(float* __restrict__ ws) {
  int g = blockIdx.x * 256 + threadIdx.x;
  int bk = g >> 11;
  int dn = g & 2047;
  const float* csa = ws + OCSA;
  const float* csb = ws + OCSB;
  float* hst = ws + OHST;
  float h = 0.f;
  for (int c = 0; c < SNC; ++c) {
    size_t idx = (size_t)(bk * SNC + c) * 2048 + dn;
    hst[idx] = h;
    h = csa[idx] * h + csb[idx];
  }
}

// ============ 7c. scan phase C ============
__global__ __launch_bounds__(256) void k_scanC(const float* __restrict__ alog,
    const float* __restrict__ Dp, float* __restrict__ ws) {
  int c = blockIdx.x, bk = blockIdx.y;
  int b = bk >> 2, k = bk & 3;
  int t = threadIdx.x;
  int n = t & 15, dg = t >> 4;
  __shared__ float dt_s[128], x_s[128], Bs_s[16], Cs_s[16];
  float A_r[8], h[8], Dv[8];
#pragma unroll
  for (int i = 0; i < 8; ++i) {
    int d = dg * 8 + i;
    A_r[i] = -__expf(alog[(size_t)((k * 128 + d) * 16) + n]);
    h[i] = ws[OHST + ((size_t)(bk * SNC + c) * 128 + d) * 16 + n];
    Dv[i] = Dp[k * 128 + d];
  }
  const float* dtp = ws + ODT2 + ((size_t)bk * Ll) * 128;
  const float* bsp = ws + OBS2 + ((size_t)bk * Ll) * 16;
  const float* csp = ws + OCS2 + ((size_t)bk * Ll) * 16;
  const float* xb = ws + OX1S + (size_t)b * Ll * 128;
  float* yp = ws + OYS2 + ((size_t)bk * Ll) * 128;
  for (int ll = 0; ll < SCH; ++ll) {
    int l = c * SCH + ll;
    int sp = spmap(k, l);
    if (t < 128) dt_s[t] = dtp[(size_t)l * 128 + t];
    else x_s[t - 128] = xb[(size_t)sp * 128 + (t - 128)];
    if (t < 16) Bs_s[t] = bsp[(size_t)l * 16 + t];
    else if (t < 32) Cs_s[t - 16] = csp[(size_t)l * 16 + (t - 16)];
    __syncthreads();
    float Bv = Bs_s[n], Cv = Cs_s[n];
    float yacc[8];
#pragma unroll
    for (int i = 0; i < 8; ++i) {
      int d = dg * 8 + i;
      float dtv = dt_s[d];
      float a = __expf(dtv * A_r[i]);
      h[i] = h[i] * a + dtv * x_s[d] * Bv;
      yacc[i] = h[i] * Cv;
    }
#pragma unroll
    for (int i = 0; i < 8; ++i) {
      float yv = yacc[i];
      yv += __shfl_xor(yv, 1, 64);
      yv += __shfl_xor(yv, 2, 64);
      yv += __shfl_xor(yv, 4, 64);
      yv += __shfl_xor(yv, 8, 64);
      yacc[i] = yv;
    }
    if (n == 0) {
#pragma unroll
      for (int i = 0; i < 8; ++i) {
        int d = dg * 8 + i;
        yp[(size_t)l * 128 + d] = yacc[i] + Dv[i] * x_s[d];
      }
    }
    __syncthreads();
  }
}

// ============ 8. combine dirs + LN + gate ============
__global__ __launch_bounds__(128) void k_comb(const float* __restrict__ nw,
    const float* __restrict__ nb, const float* __restrict__ snr,
    float* __restrict__ ws) {
  int l = blockIdx.x, b = blockIdx.y, d = threadIdx.x;
  int h = l / 48, w = l % 48;
  int lT = w * 48 + h;
  const float* ysb = ws + OYS2;
  float v = ysb[((size_t)(b * 4 + 0) * Ll + l) * 128 + d] +
            ysb[((size_t)(b * 4 + 2) * Ll + (2303 - l)) * 128 + d] +
            ysb[((size_t)(b * 4 + 1) * Ll + lT) * 128 + d] +
            ysb[((size_t)(b * 4 + 3) * Ll + (2303 - lT)) * 128 + d];
  __shared__ float red[4];
  int lane = d & 63, wid = d >> 6;
  float s = v;
#pragma unroll
  for (int o = 32; o >= 1; o >>= 1) s += __shfl_xor(s, o, 64);
  if (lane == 0) red[wid] = s;
  __syncthreads();
  float m = (red[0] + red[1]) * (1.f / 128.f);
  float dv_ = v - m;
  float q = dv_ * dv_;
#pragma unroll
  for (int o = 32; o >= 1; o >>= 1) q += __shfl_xor(q, o, 64);
  if (lane == 0) red[wid + 2] = q;
  __syncthreads();
  float var = (red[2] + red[3]) * (1.f / 128.f);
  float y = dv_ * rsqrtf(var + 1e-5f) * nw[d] + nb[d];
  float zv = ws[OZ + ((size_t)b * Ll + l) * 128 + d];
  y *= siluf(zv);
  y *= snr[b * Ll + l];
  ws[OY2 + ((size_t)b * Ll + l) * 128 + d] = y;
}

// ============ 9+10. x2 + LN + FFN conv1 + gelu (fused) ============
__global__ __launch_bounds__(256) void k_outffn1(const float* __restrict__ enc,
    const float* __restrict__ ow, const float* __restrict__ lw,
    const float* __restrict__ lb, const float* __restrict__ w1,
    float* __restrict__ ws) {
  int l = blockIdx.x, b = blockIdx.y, t = threadIdx.x;
  __shared__ float yr[128];
  __shared__ float part[2][64];
  __shared__ float xn_s[64];
  const float* yp = ws + OY2 + ((size_t)b * Ll + l) * 128;
  if (t < 128) yr[t] = yp[t];
  __syncthreads();
  if (t < 128) {
    int col = t & 63, seg = t >> 6;
    float p = 0.f;
    const float* ows = ow + (size_t)(seg * 64) * 64 + col;
#pragma unroll 8
    for (int dd = 0; dd < 64; ++dd) p += yr[seg * 64 + dd] * ows[dd * 64];
    part[seg][col] = p;
  }
  __syncthreads();
  if (t < 64) {
    float acc = part[0][t] + part[1][t];
    acc += enc[(size_t)b * Cc * Ll + (size_t)t * Ll + l];
    ws[OX2 + ((size_t)b * Ll + l) * 64 + t] = acc;
    float s = acc;
#pragma unroll
    for (int o = 32; o >= 1; o >>= 1) s += __shfl_xor(s, o, 64);
    float m = s * (1.f / 64.f);
    float dd2 = acc - m;
    float vs = dd2 * dd2;
#pragma unroll
    for (int o = 32; o >= 1; o >>= 1) vs += __shfl_xor(vs, o, 64);
    float var = vs * (1.f / 64.f);
    xn_s[t] = dd2 * rsqrtf(var + 1e-5f) * lw[t] + lb[t];
  }
  __syncthreads();
  float acc2 = 0.f;
  const float* wp = w1 + (size_t)t * 64;
#pragma unroll 8
  for (int c = 0; c < 64; ++c) acc2 += xn_s[c] * wp[c];
  ws[OH1A + ((size_t)b * Ll + l) * 256 + t] = geluf(acc2);
}

// ============ 11. FFN depthwise 3x3 + gelu ============
__global__ __launch_bounds__(256) void k_ffndw(const float* __restrict__ dww,
                                               float* __restrict__ ws) {
  int l = blockIdx.x, b = blockIdx.y, mch = threadIdx.x;
  int h = l / 48, w = l % 48;
  float acc = 0.f;
#pragma unroll
  for (int kh = 0; kh < 3; ++kh) {
    int hh = h + kh - 1;
    if (hh < 0 || hh >= 48) continue;
#pragma unroll
    for (int kw = 0; kw < 3; ++kw) {
      int wx = w + kw - 1;
      if (wx < 0 || wx >= 48) continue;
      acc += ws[OH1A + ((size_t)b * Ll + hh * 48 + wx) * 256 + mch] *
             dww[mch * 9 + kh * 3 + kw];
    }
  }
  ws[OH1B + ((size_t)b * Ll + l) * 256 + mch] = geluf(acc);
}

// ============ 12. FFN conv2 1x1 + residual ============
__global__ __launch_bounds__(64) void k_ffn2(const float* __restrict__ w2,
                                             float* __restrict__ ws) {
  int l = blockIdx.x, b = blockIdx.y, c = threadIdx.x;
  __shared__ float hr[256];
  const float* hp = ws + OH1B + ((size_t)b * Ll + l) * 256;
  for (int i = c; i < 256; i += 64) hr[i] = hp[i];
  __syncthreads();
  float acc = 0.f;
  const float* wp = w2 + (size_t)c * 256;
#pragma unroll 8
  for (int mm = 0; mm < 256; ++mm) acc += hr[mm] * wp[mm];
  acc += ws[OX2 + ((size_t)b * Ll + l) * 64 + c];
  ws[OX3 + ((size_t)b * Ll + l) * 64 + c] = acc;
}

// ============ 13. transpose (B,L,C) -> (B,C,L) fp32 out ============
__global__ __launch_bounds__(256) void k_trout(const float* __restrict__ ws,
                                               float* __restrict__ out) {
  int b = blockIdx.y;
  int l0 = blockIdx.x * 64;
  int t = threadIdx.x;
  __shared__ float tile[64][65];
  const float* xp = ws + OX3 + ((size_t)b * Ll + l0) * 64;
  for (int i = t; i < 4096; i += 256) tile[i >> 6][i & 63] = xp[i];
  __syncthreads();
  for (int i = t; i < 4096; i += 256) {
    int c = i >> 6, li = i & 63;
    out[((size_t)(b * 64 + c)) * 2304 + l0 + li] = tile[li][c];
  }
}

extern "C" void kernel_launch(void* const* d_in, const int* in_sizes, int n_in,
                              void* d_out, int out_size, void* d_ws, size_t ws_size,
                              hipStream_t stream) {
  (void)in_sizes; (void)n_in; (void)out_size;
  const float* enc  = (const float*)d_in[0];
  const float* snr  = (const float*)d_in[1];
  const float* wq   = (const float*)d_in[2];
  const float* wk   = (const float*)d_in[3];
  const float* wv   = (const float*)d_in[4];
  const float* fc   = (const float*)d_in[5];
  const float* alnw = (const float*)d_in[6];
  const float* alnb = (const float*)d_in[7];
  const float* ssin = (const float*)d_in[8];
  const float* cw   = (const float*)d_in[9];
  const float* cb   = (const float*)d_in[10];
  const float* xw   = (const float*)d_in[11];
  const float* dtw  = (const float*)d_in[12];
  const float* dtb  = (const float*)d_in[13];
  const float* alog = (const float*)d_in[14];
  const float* Dp   = (const float*)d_in[15];
  const float* nw   = (const float*)d_in[16];
  const float* nb   = (const float*)d_in[17];
  const float* ow   = (const float*)d_in[18];
  const float* flnw = (const float*)d_in[19];
  const float* flnb = (const float*)d_in[20];
  const float* w1   = (const float*)d_in[21];
  const float* dww  = (const float*)d_in[22];
  const float* w2   = (const float*)d_in[23];
  float* ws = (float*)d_ws;
  float* out = (float*)d_out;

  if (ws_size < (size_t)WS_NEED_FLOATS * 4) {
    hipLaunchKernelGGL(k_code, dim3(1), dim3(64), 0, stream, out);
    return;
  }

  hipLaunchKernelGGL(k_qkv, dim3(Bq * Ll), dim3(256), 0, stream, enc, wq, wk, wv, ws);
  hipLaunchKernelGGL(k_vt, dim3(Ll / 64, Bq * NHh), dim3(256), 0, stream, ws);
  hipLaunchKernelGGL(k_attn, dim3(Ll / 64, Bq * NHh), dim3(256), 0, stream, snr, ws);
  hipLaunchKernelGGL(k_oprojxz, dim3(Ll, Bq), dim3(256), 0, stream, enc, fc, alnw, alnb, ssin, ws);
  hipLaunchKernelGGL(k_conv, dim3(Ll, Bq), dim3(128), 0, stream, cw, cb, ws);
  hipLaunchKernelGGL(k_xdbl, dim3(Ll, Bq * 4), dim3(128), 0, stream, xw, dtw, dtb, ws);
  hipLaunchKernelGGL(k_scanA, dim3(SNC, Bq * 4), dim3(256), 0, stream, alog, ws);
  hipLaunchKernelGGL(k_scanB, dim3(64), dim3(256), 0, stream, ws);
  hipLaunchKernelGGL(k_scanC, dim3(SNC, Bq * 4), dim3(256), 0, stream, alog, Dp, ws);
  hipLaunchKernelGGL(k_comb, dim3(Ll, Bq), dim3(128), 0, stream, nw, nb, snr, ws);
  hipLaunchKernelGGL(k_outffn1, dim3(Ll, Bq), dim3(256), 0, stream, enc, ow, flnw, flnb, w1, ws);
  hipLaunchKernelGGL(k_ffndw, dim3(Ll, Bq), dim3(256), 0, stream, dww, ws);
  hipLaunchKernelGGL(k_ffn2, dim3(Ll, Bq), dim3(64), 0, stream, w2, ws);
  hipLaunchKernelGGL(k_trout, dim3(Ll / 64, Bq), dim3(256), 0, stream, ws, out);
}

// Round 9
// 642.289 us; speedup vs baseline: 3.9802x; 1.0772x over previous
//
#include <hip/hip_runtime.h>
#include <hip/hip_bf16.h>

#define Bq 2
#define Cc 64
#define Hh 48
#define Ww 48
#define Ll 2304
#define NHh 8
#define DKk 64
#define DVv 128
#define DNn 128
#define NSs 16
#define Rr 4
#define SCH 48
#define SNC 48

// ---- workspace layout (float offsets) ----
#define OQ    0u                 // (B*8, L, 64) Q bf16 (ushort), pre-scaled by 1/8
#define OK_   2359296u           // (B*8, L, 64) K bf16 (ushort)
#define OV    4718592u           // (B*8, L, 128) V fp32
#define OO    9437184u           // (B, L, 1024) attention out fp32
#define OY2   14450688u
#define OX2   15040512u
#define OXN   15335424u
#define OVT   15630336u          // (B*8, 128, L) V^T bf16 (ushort)
#define WS_NEED_FLOATS (OVT + 4718592u)
// aliases (lifetimes: q,k,v,vt dead after k_attn; o dead after k_oprojxz)
#define ODT2  OQ                 // (B*4, L, 128) dt, l-major
#define OYS2  OK_                // (B*4, L, 128) scan y, l-major
#define OX1P  OV                 // (B,L,128)
#define OZ    (OV + 589824u)     // (B,L,128)
#define OX1S  (OV + 1179648u)    // (B,L,128)
#define OBS2  (OV + 1769472u)    // (B*4, L, 16)
#define OCS2  (OV + 2064384u)    // (B*4, L, 16)
#define OCSA  (OV + 2359296u)    // (B*4, SNC, 128, 16)
#define OCSB  (OV + 3145728u)    // (B*4, SNC, 128, 16)
#define OHST  (OV + 3932160u)    // (B*4, SNC, 128, 16)
#define OH1A  OO                 // (B,L,256)
#define OH1B  (OO + 1179648u)    // (B,L,256)
#define OX3   (OO + 2359296u)    // (B,L,64)

typedef short short8v __attribute__((ext_vector_type(8)));
typedef short short4v __attribute__((ext_vector_type(4)));
typedef float f32x4 __attribute__((ext_vector_type(4)));
typedef unsigned short ushort_t;

__device__ __forceinline__ float geluf(float x) {
  return 0.5f * x * (1.0f + erff(x * 0.70710678118654752f));
}
__device__ __forceinline__ float siluf(float x) {
  return x / (1.0f + __expf(-x));
}
__device__ __forceinline__ float softplusf(float x) {
  return fmaxf(x, 0.0f) + log1pf(__expf(-fabsf(x)));
}
__device__ __forceinline__ int spmap(int k, int l) {
  if (k == 0) return l;
  if (k == 1) return (l % 48) * 48 + l / 48;
  if (k == 2) return 2303 - l;
  int l2 = 2303 - l; return (l2 % 48) * 48 + l2 / 48;
}
__device__ __forceinline__ short f2bf(float f) {
  unsigned u = __float_as_uint(f);
  unsigned r = (u + 0x7FFFu + ((u >> 16) & 1u)) >> 16;
  return (short)r;
}

__global__ void k_code(float* out) { if (threadIdx.x == 0) out[0] = 25000.f; }

// ============ 1. QKV projection (Q bf16 pre-scaled 1/8, K bf16, V fp32) ============
__global__ __launch_bounds__(256) void k_qkv(const float* __restrict__ enc,
    const float* __restrict__ wq, const float* __restrict__ wk,
    const float* __restrict__ wv, float* __restrict__ ws) {
  int bl = blockIdx.x; int b = bl / Ll; int l = bl % Ll;
  int t = threadIdx.x;
  __shared__ float xr[64];
  if (t < 64) xr[t] = enc[(size_t)b * Cc * Ll + (size_t)t * Ll + l];
  __syncthreads();
  ushort_t* qb = (ushort_t*)(ws + OQ);
  ushort_t* kb = (ushort_t*)(ws + OK_);
  float* v = ws + OV;
#pragma unroll
  for (int i = 0; i < 8; ++i) {
    int j = t + i * 256;
    float acc = 0.f;
    if (j < 512) {
      const float* wp = wq; int col = j;
#pragma unroll 8
      for (int c = 0; c < 64; ++c) acc += xr[c] * wp[c * 512 + col];
      qb[((size_t)(b * 8 + (col >> 6)) * Ll + l) * 64 + (col & 63)] =
          (ushort_t)f2bf(acc * 0.125f);
    } else if (j < 1024) {
      const float* wp = wk; int col = j - 512;
#pragma unroll 8
      for (int c = 0; c < 64; ++c) acc += xr[c] * wp[c * 512 + col];
      kb[((size_t)(b * 8 + (col >> 6)) * Ll + l) * 64 + (col & 63)] = (ushort_t)f2bf(acc);
    } else {
      const float* wp = wv; int col = j - 1024;
#pragma unroll 8
      for (int c = 0; c < 64; ++c) acc += xr[c] * wp[c * 1024 + col];
      v[((size_t)(b * 8 + (col >> 7)) * Ll + l) * 128 + (col & 127)] = acc;
    }
  }
}

// ============ 1b. transpose V -> vt bf16 (bh, dv, L) ============
__global__ __launch_bounds__(256) void k_vt(float* __restrict__ ws) {
  int bh = blockIdx.y;
  int l0 = blockIdx.x * 64;
  int t = threadIdx.x;
  __shared__ float tile[128][65];
  const float* vp = ws + OV + ((size_t)bh * Ll + l0) * 128;
  for (int i = t; i < 64 * 32; i += 256) {
    int l = i >> 5, dv4 = (i & 31) * 4;
    float4 a = *(const float4*)(vp + (size_t)l * 128 + dv4);
    tile[dv4][l] = a.x; tile[dv4 + 1][l] = a.y;
    tile[dv4 + 2][l] = a.z; tile[dv4 + 3][l] = a.w;
  }
  __syncthreads();
  ushort_t* vt = (ushort_t*)(ws + OVT) + (size_t)bh * 128 * Ll + l0;
  for (int i = t; i < 128 * 16; i += 256) {
    int dv = i >> 4, l4 = (i & 15) * 4;
    short4v a;
    a[0] = f2bf(tile[dv][l4]); a[1] = f2bf(tile[dv][l4 + 1]);
    a[2] = f2bf(tile[dv][l4 + 2]); a[3] = f2bf(tile[dv][l4 + 3]);
    *(short4v*)(vt + (size_t)dv * Ll + l4) = a;
  }
}

// ============ 2. flash attention (bf16 MFMA, 64-key tiles, reg-prefetch) ============
#define NKT 36   // Ll/64 iterations
#define LSK 72   // Ks/Vs/Ps row stride (ushort)
__global__ __launch_bounds__(256) void k_attn(const float* __restrict__ snr,
                                              float* __restrict__ ws) {
  int bh = blockIdx.y; int b = bh >> 3; int hd = bh & 7;
  int q0 = blockIdx.x * 64;
  int t = threadIdx.x;
  int w = t >> 6, lane = t & 63;
  int m16 = lane & 15, quad = lane >> 4;

  __shared__ __align__(16) ushort_t Ks[64 * LSK];      // [key][d]
  __shared__ __align__(16) ushort_t Vs[128 * LSK];     // [dv][key]
  __shared__ __align__(16) ushort_t Ps[4 * 16 * LSK];  // per-wave [qrow][key]
  __shared__ float lsn_s[64];
  __shared__ float asc[4][16];
  __shared__ float lsc[4][16];

  const ushort_t* qbf = (const ushort_t*)(ws + OQ) + (size_t)bh * Ll * 64;
  const ushort_t* kbf = (const ushort_t*)(ws + OK_) + (size_t)bh * Ll * 64;
  const ushort_t* vtb = (const ushort_t*)(ws + OVT) + (size_t)bh * 128 * Ll;

  short8v qa[2];
  {
    const ushort_t* qrp = qbf + (size_t)(q0 + w * 16 + m16) * 64 + quad * 8;
    qa[0] = *(const short8v*)qrp;
    qa[1] = *(const short8v*)(qrp + 32);
  }
  // staging assignments
  int sk_key = t >> 2, sk_d0 = (t & 3) * 16;   // K: 64 keys x 64 d
  int sv_dv = t >> 1, sv_k0 = (t & 1) * 32;    // V^T: 128 dv x 64 keys

  short8v kreg[2], vreg[4];
  float snr_reg = 0.f;
  {
    const ushort_t* ksrc = kbf + (size_t)sk_key * 64 + sk_d0;
    kreg[0] = *(const short8v*)ksrc;
    kreg[1] = *(const short8v*)(ksrc + 8);
    const ushort_t* vsrc = vtb + (size_t)sv_dv * Ll + sv_k0;
#pragma unroll
    for (int i = 0; i < 4; ++i) vreg[i] = *(const short8v*)(vsrc + i * 8);
    if (t < 64) snr_reg = snr[b * Ll + t];
  }

  f32x4 oacc[8];
#pragma unroll
  for (int i = 0; i < 8; ++i) oacc[i] = (f32x4)0.f;
  float m_r[4] = {-1e30f, -1e30f, -1e30f, -1e30f};
  float l_r[4] = {0.f, 0.f, 0.f, 0.f};

  for (int kt = 0; kt < NKT; ++kt) {
    __syncthreads();
    *(short8v*)&Ks[sk_key * LSK + sk_d0] = kreg[0];
    *(short8v*)&Ks[sk_key * LSK + sk_d0 + 8] = kreg[1];
#pragma unroll
    for (int i = 0; i < 4; ++i)
      *(short8v*)&Vs[sv_dv * LSK + sv_k0 + i * 8] = vreg[i];
    if (t < 64) lsn_s[t] = logf(snr_reg + 1e-4f);
    __syncthreads();
    if (kt + 1 < NKT) {
      int k0n = (kt + 1) * 64;
      const ushort_t* ksrc = kbf + (size_t)(k0n + sk_key) * 64 + sk_d0;
      kreg[0] = *(const short8v*)ksrc;
      kreg[1] = *(const short8v*)(ksrc + 8);
      const ushort_t* vsrc = vtb + (size_t)sv_dv * Ll + k0n + sv_k0;
#pragma unroll
      for (int i = 0; i < 4; ++i) vreg[i] = *(const short8v*)(vsrc + i * 8);
      if (t < 64) snr_reg = snr[b * Ll + k0n + t];
    }

    // QK^T: 4 N-tiles of 16 keys (Q pre-scaled by 1/8)
    f32x4 sac[4];
#pragma unroll
    for (int n = 0; n < 4; ++n) {
      int key = n * 16 + m16;
      short8v kb0 = *(const short8v*)&Ks[key * LSK + quad * 8];
      short8v kb1 = *(const short8v*)&Ks[key * LSK + 32 + quad * 8];
      f32x4 acc = (f32x4)0.f;
      acc = __builtin_amdgcn_mfma_f32_16x16x32_bf16(qa[0], kb0, acc, 0, 0, 0);
      acc = __builtin_amdgcn_mfma_f32_16x16x32_bf16(qa[1], kb1, acc, 0, 0, 0);
      sac[n] = acc;
    }
    float lsv[4];
#pragma unroll
    for (int n = 0; n < 4; ++n) lsv[n] = lsn_s[n * 16 + m16];
    ushort_t* pw = &Ps[w * 16 * LSK];
    float alpha[4];
#pragma unroll
    for (int r = 0; r < 4; ++r) {
      float s[4], p[4];
#pragma unroll
      for (int n = 0; n < 4; ++n) s[n] = sac[n][r] + lsv[n];
      float mx = fmaxf(fmaxf(s[0], s[1]), fmaxf(s[2], s[3]));
      mx = fmaxf(mx, __shfl_xor(mx, 1, 64));
      mx = fmaxf(mx, __shfl_xor(mx, 2, 64));
      mx = fmaxf(mx, __shfl_xor(mx, 4, 64));
      mx = fmaxf(mx, __shfl_xor(mx, 8, 64));
      float nm = fmaxf(m_r[r], mx);
      alpha[r] = __expf(m_r[r] - nm);
      m_r[r] = nm;
      float rs = 0.f;
#pragma unroll
      for (int n = 0; n < 4; ++n) { p[n] = __expf(s[n] - nm); rs += p[n]; }
      rs += __shfl_xor(rs, 1, 64);
      rs += __shfl_xor(rs, 2, 64);
      rs += __shfl_xor(rs, 4, 64);
      rs += __shfl_xor(rs, 8, 64);
      l_r[r] = l_r[r] * alpha[r] + rs;
#pragma unroll
      for (int n = 0; n < 4; ++n)
        pw[(quad * 4 + r) * LSK + n * 16 + m16] = (ushort_t)f2bf(p[n]);
    }
    if (m16 == 0) {
#pragma unroll
      for (int r = 0; r < 4; ++r) asc[w][quad * 4 + r] = alpha[r];
    }
    float av = asc[w][m16];
    short8v pb0 = *(const short8v*)&pw[m16 * LSK + quad * 8];
    short8v pb1 = *(const short8v*)&pw[m16 * LSK + 32 + quad * 8];
#pragma unroll
    for (int dt_ = 0; dt_ < 8; ++dt_) {
      const ushort_t* vrow = &Vs[(dt_ * 16 + m16) * LSK];
      short8v va0 = *(const short8v*)&vrow[quad * 8];
      short8v va1 = *(const short8v*)&vrow[32 + quad * 8];
      f32x4 o = oacc[dt_];
      o[0] *= av; o[1] *= av; o[2] *= av; o[3] *= av;
      o = __builtin_amdgcn_mfma_f32_16x16x32_bf16(va0, pb0, o, 0, 0, 0);
      o = __builtin_amdgcn_mfma_f32_16x16x32_bf16(va1, pb1, o, 0, 0, 0);
      oacc[dt_] = o;
    }
  }
  if (m16 == 0) {
#pragma unroll
    for (int r = 0; r < 4; ++r) lsc[w][quad * 4 + r] = l_r[r];
  }
  float linv = 1.f / lsc[w][m16];
  float* op = ws + OO + ((size_t)(b * Ll + q0 + w * 16 + m16)) * 1024 + hd * 128;
#pragma unroll
  for (int dt_ = 0; dt_ < 8; ++dt_) {
#pragma unroll
    for (int r = 0; r < 4; ++r) {
      op[dt_ * 16 + quad * 4 + r] = oacc[dt_][r] * linv;
    }
  }
}

// ============ 3+4. o@fc + residual + LN + xz projection (fused) ============
__global__ __launch_bounds__(256) void k_oprojxz(const float* __restrict__ enc,
    const float* __restrict__ fc, const float* __restrict__ lnw,
    const float* __restrict__ lnb, const float* __restrict__ ssin,
    float* __restrict__ ws) {
  int l = blockIdx.x, b = blockIdx.y, t = threadIdx.x;
  __shared__ float orow[1024];
  __shared__ float part[4][64];
  __shared__ float xh_s[64];
  const float* op = ws + OO + ((size_t)b * Ll + l) * 1024;
#pragma unroll
  for (int i = 0; i < 4; ++i) orow[t + i * 256] = op[t + i * 256];
  __syncthreads();
  int col = t & 63, seg = t >> 6;
  {
    float p = 0.f;
    const float* fcs = fc + (size_t)(seg * 256) * 64 + col;
#pragma unroll 8
    for (int j = 0; j < 256; ++j) p += orow[seg * 256 + j] * fcs[j * 64];
    part[seg][col] = p;
  }
  __syncthreads();
  if (t < 64) {
    float acc = part[0][t] + part[1][t] + part[2][t] + part[3][t];
    acc += enc[(size_t)b * Cc * Ll + (size_t)t * Ll + l];
    float s = acc;
#pragma unroll
    for (int o = 32; o >= 1; o >>= 1) s += __shfl_xor(s, o, 64);
    float m = s * (1.f / 64.f);
    float dd = acc - m;
    float vs = dd * dd;
#pragma unroll
    for (int o = 32; o >= 1; o >>= 1) vs += __shfl_xor(vs, o, 64);
    float var = vs * (1.f / 64.f);
    xh_s[t] = dd * rsqrtf(var + 1e-5f) * lnw[t] + lnb[t];
  }
  __syncthreads();
  float acc2 = 0.f;
#pragma unroll 8
  for (int c = 0; c < 64; ++c) acc2 += xh_s[c] * ssin[c * 256 + t];
  if (t < 128) ws[OX1P + ((size_t)b * Ll + l) * 128 + t] = acc2;
  else ws[OZ + ((size_t)b * Ll + l) * 128 + (t - 128)] = acc2;
}

// ============ 5. depthwise conv3x3 + bias + silu ============
__global__ __launch_bounds__(128) void k_conv(const float* __restrict__ cw,
    const float* __restrict__ cb, float* __restrict__ ws) {
  int l = blockIdx.x, b = blockIdx.y, d = threadIdx.x;
  int h = l / 48, w = l % 48;
  float acc = cb[d];
#pragma unroll
  for (int kh = 0; kh < 3; ++kh) {
    int hh = h + kh - 1;
    if (hh < 0 || hh >= 48) continue;
#pragma unroll
    for (int kw = 0; kw < 3; ++kw) {
      int wx = w + kw - 1;
      if (wx < 0 || wx >= 48) continue;
      acc += ws[OX1P + ((size_t)b * Ll + hh * 48 + wx) * 128 + d] *
             cw[d * 9 + kh * 3 + kw];
    }
  }
  ws[OX1S + ((size_t)b * Ll + l) * 128 + d] = siluf(acc);
}

// ============ 6. x_dbl projections -> dt2/Bs2/Cs2 (l-major) ============
__global__ __launch_bounds__(128) void k_xdbl(const float* __restrict__ xw,
    const float* __restrict__ dtw, const float* __restrict__ dtb,
    float* __restrict__ ws) {
  int l = blockIdx.x;
  int by = blockIdx.y; int b = by >> 2; int k = by & 3;
  int t = threadIdx.x;
  int sp = spmap(k, l);
  __shared__ float xv[128];
  __shared__ float pr[36];
  xv[t] = ws[OX1S + ((size_t)b * Ll + sp) * 128 + t];
  __syncthreads();
  if (t < 36) {
    float s = 0.f;
    const float* wp = xw + (size_t)(k * 36 + t) * 128;
#pragma unroll 8
    for (int d = 0; d < 128; ++d) s += xv[d] * wp[d];
    pr[t] = s;
  }
  __syncthreads();
  {
    int d = t;
    const float* wp = dtw + (size_t)(k * 128 + d) * 4;
    float v = pr[0] * wp[0] + pr[1] * wp[1] +
              pr[2] * wp[2] + pr[3] * wp[3] + dtb[k * 128 + d];
    ws[ODT2 + ((size_t)by * Ll + l) * 128 + d] = softplusf(v);
  }
  if (t < 16) ws[OBS2 + ((size_t)by * Ll + l) * 16 + t] = pr[4 + t];
  else if (t < 32) ws[OCS2 + ((size_t)by * Ll + l) * 16 + (t - 16)] = pr[20 + (t - 16)];
}

// ============ 7a. scan phase A ============
__global__ __launch_bounds__(256) void k_scanA(const float* __restrict__ alog,
                                               float* __restrict__ ws) {
  int c = blockIdx.x;
  int bk = blockIdx.y;
  int b = bk >> 2, k = bk & 3;
  int t = threadIdx.x;
  int n = t & 15, dg = t >> 4;
  __shared__ float dt_s[128], x_s[128], Bs_s[16];
  float A_r[8], ap[8], bc[8];
#pragma unroll
  for (int i = 0; i < 8; ++i) {
    int d = dg * 8 + i;
    A_r[i] = -__expf(alog[(size_t)((k * 128 + d) * 16) + n]);
    ap[i] = 1.f; bc[i] = 0.f;
  }
  const float* dtp = ws + ODT2 + ((size_t)bk * Ll) * 128;
  const float* bsp = ws + OBS2 + ((size_t)bk * Ll) * 16;
  const float* xb = ws + OX1S + (size_t)b * Ll * 128;
  for (int ll = 0; ll < SCH; ++ll) {
    int l = c * SCH + ll;
    int sp = spmap(k, l);
    if (t < 128) dt_s[t] = dtp[(size_t)l * 128 + t];
    else x_s[t - 128] = xb[(size_t)sp * 128 + (t - 128)];
    if (t < 16) Bs_s[t] = bsp[(size_t)l * 16 + t];
    __syncthreads();
    float Bv = Bs_s[n];
#pragma unroll
    for (int i = 0; i < 8; ++i) {
      int d = dg * 8 + i;
      float dtv = dt_s[d];
      float a = __expf(dtv * A_r[i]);
      bc[i] = bc[i] * a + dtv * x_s[d] * Bv;
      ap[i] *= a;
    }
    __syncthreads();
  }
  float* csa = ws + OCSA + ((size_t)(bk * SNC + c) * 128) * 16;
  float* csb = ws + OCSB + ((size_t)(bk * SNC + c) * 128) * 16;
#pragma unroll
  for (int i = 0; i < 8; ++i) {
    int d = dg * 8 + i;
    csa[d * 16 + n] = ap[i];
    csb[d * 16 + n] = bc[i];
  }
}

// ============ 7b. scan phase B ============
__global__ __launch_bounds__(256) void k_scanB(float* __restrict__ ws) {
  int g = blockIdx.x * 256 + threadIdx.x;
  int bk = g >> 11;
  int dn = g & 2047;
  const float* csa = ws + OCSA;
  const float* csb = ws + OCSB;
  float* hst = ws + OHST;
  float h = 0.f;
  for (int c = 0; c < SNC; ++c) {
    size_t idx = (size_t)(bk * SNC + c) * 2048 + dn;
    hst[idx] = h;
    h = csa[idx] * h + csb[idx];
  }
}

// ============ 7c. scan phase C ============
__global__ __launch_bounds__(256) void k_scanC(const float* __restrict__ alog,
    const float* __restrict__ Dp, float* __restrict__ ws) {
  int c = blockIdx.x, bk = blockIdx.y;
  int b = bk >> 2, k = bk & 3;
  int t = threadIdx.x;
  int n = t & 15, dg = t >> 4;
  __shared__ float dt_s[128], x_s[128], Bs_s[16], Cs_s[16];
  float A_r[8], h[8], Dv[8];
#pragma unroll
  for (int i = 0; i < 8; ++i) {
    int d = dg * 8 + i;
    A_r[i] = -__expf(alog[(size_t)((k * 128 + d) * 16) + n]);
    h[i] = ws[OHST + ((size_t)(bk * SNC + c) * 128 + d) * 16 + n];
    Dv[i] = Dp[k * 128 + d];
  }
  const float* dtp = ws + ODT2 + ((size_t)bk * Ll) * 128;
  const float* bsp = ws + OBS2 + ((size_t)bk * Ll) * 16;
  const float* csp = ws + OCS2 + ((size_t)bk * Ll) * 16;
  const float* xb = ws + OX1S + (size_t)b * Ll * 128;
  float* yp = ws + OYS2 + ((size_t)bk * Ll) * 128;
  for (int ll = 0; ll < SCH; ++ll) {
    int l = c * SCH + ll;
    int sp = spmap(k, l);
    if (t < 128) dt_s[t] = dtp[(size_t)l * 128 + t];
    else x_s[t - 128] = xb[(size_t)sp * 128 + (t - 128)];
    if (t < 16) Bs_s[t] = bsp[(size_t)l * 16 + t];
    else if (t < 32) Cs_s[t - 16] = csp[(size_t)l * 16 + (t - 16)];
    __syncthreads();
    float Bv = Bs_s[n], Cv = Cs_s[n];
    float yacc[8];
#pragma unroll
    for (int i = 0; i < 8; ++i) {
      int d = dg * 8 + i;
      float dtv = dt_s[d];
      float a = __expf(dtv * A_r[i]);
      h[i] = h[i] * a + dtv * x_s[d] * Bv;
      yacc[i] = h[i] * Cv;
    }
#pragma unroll
    for (int i = 0; i < 8; ++i) {
      float yv = yacc[i];
      yv += __shfl_xor(yv, 1, 64);
      yv += __shfl_xor(yv, 2, 64);
      yv += __shfl_xor(yv, 4, 64);
      yv += __shfl_xor(yv, 8, 64);
      yacc[i] = yv;
    }
    if (n == 0) {
#pragma unroll
      for (int i = 0; i < 8; ++i) {
        int d = dg * 8 + i;
        yp[(size_t)l * 128 + d] = yacc[i] + Dv[i] * x_s[d];
      }
    }
    __syncthreads();
  }
}

// ============ 8. combine dirs + LN + gate ============
__global__ __launch_bounds__(128) void k_comb(const float* __restrict__ nw,
    const float* __restrict__ nb, const float* __restrict__ snr,
    float* __restrict__ ws) {
  int l = blockIdx.x, b = blockIdx.y, d = threadIdx.x;
  int h = l / 48, w = l % 48;
  int lT = w * 48 + h;
  const float* ysb = ws + OYS2;
  float v = ysb[((size_t)(b * 4 + 0) * Ll + l) * 128 + d] +
            ysb[((size_t)(b * 4 + 2) * Ll + (2303 - l)) * 128 + d] +
            ysb[((size_t)(b * 4 + 1) * Ll + lT) * 128 + d] +
            ysb[((size_t)(b * 4 + 3) * Ll + (2303 - lT)) * 128 + d];
  __shared__ float red[4];
  int lane = d & 63, wid = d >> 6;
  float s = v;
#pragma unroll
  for (int o = 32; o >= 1; o >>= 1) s += __shfl_xor(s, o, 64);
  if (lane == 0) red[wid] = s;
  __syncthreads();
  float m = (red[0] + red[1]) * (1.f / 128.f);
  float dv_ = v - m;
  float q = dv_ * dv_;
#pragma unroll
  for (int o = 32; o >= 1; o >>= 1) q += __shfl_xor(q, o, 64);
  if (lane == 0) red[wid + 2] = q;
  __syncthreads();
  float var = (red[2] + red[3]) * (1.f / 128.f);
  float y = dv_ * rsqrtf(var + 1e-5f) * nw[d] + nb[d];
  float zv = ws[OZ + ((size_t)b * Ll + l) * 128 + d];
  y *= siluf(zv);
  y *= snr[b * Ll + l];
  ws[OY2 + ((size_t)b * Ll + l) * 128 + d] = y;
}

// ============ 9+10. x2 + LN + FFN conv1 + gelu (fused) ============
__global__ __launch_bounds__(256) void k_outffn1(const float* __restrict__ enc,
    const float* __restrict__ ow, const float* __restrict__ lw,
    const float* __restrict__ lb, const float* __restrict__ w1,
    float* __restrict__ ws) {
  int l = blockIdx.x, b = blockIdx.y, t = threadIdx.x;
  __shared__ float yr[128];
  __shared__ float part[2][64];
  __shared__ float xn_s[64];
  const float* yp = ws + OY2 + ((size_t)b * Ll + l) * 128;
  if (t < 128) yr[t] = yp[t];
  __syncthreads();
  if (t < 128) {
    int col = t & 63, seg = t >> 6;
    float p = 0.f;
    const float* ows = ow + (size_t)(seg * 64) * 64 + col;
#pragma unroll 8
    for (int dd = 0; dd < 64; ++dd) p += yr[seg * 64 + dd] * ows[dd * 64];
    part[seg][col] = p;
  }
  __syncthreads();
  if (t < 64) {
    float acc = part[0][t] + part[1][t];
    acc += enc[(size_t)b * Cc * Ll + (size_t)t * Ll + l];
    ws[OX2 + ((size_t)b * Ll + l) * 64 + t] = acc;
    float s = acc;
#pragma unroll
    for (int o = 32; o >= 1; o >>= 1) s += __shfl_xor(s, o, 64);
    float m = s * (1.f / 64.f);
    float dd2 = acc - m;
    float vs = dd2 * dd2;
#pragma unroll
    for (int o = 32; o >= 1; o >>= 1) vs += __shfl_xor(vs, o, 64);
    float var = vs * (1.f / 64.f);
    xn_s[t] = dd2 * rsqrtf(var + 1e-5f) * lw[t] + lb[t];
  }
  __syncthreads();
  float acc2 = 0.f;
  const float* wp = w1 + (size_t)t * 64;
#pragma unroll 8
  for (int c = 0; c < 64; ++c) acc2 += xn_s[c] * wp[c];
  ws[OH1A + ((size_t)b * Ll + l) * 256 + t] = geluf(acc2);
}

// ============ 11. FFN depthwise 3x3 + gelu ============
__global__ __launch_bounds__(256) void k_ffndw(const float* __restrict__ dww,
                                               float* __restrict__ ws) {
  int l = blockIdx.x, b = blockIdx.y, mch = threadIdx.x;
  int h = l / 48, w = l % 48;
  float acc = 0.f;
#pragma unroll
  for (int kh = 0; kh < 3; ++kh) {
    int hh = h + kh - 1;
    if (hh < 0 || hh >= 48) continue;
#pragma unroll
    for (int kw = 0; kw < 3; ++kw) {
      int wx = w + kw - 1;
      if (wx < 0 || wx >= 48) continue;
      acc += ws[OH1A + ((size_t)b * Ll + hh * 48 + wx) * 256 + mch] *
             dww[mch * 9 + kh * 3 + kw];
    }
  }
  ws[OH1B + ((size_t)b * Ll + l) * 256 + mch] = geluf(acc);
}

// ============ 12. FFN conv2 1x1 + residual ============
__global__ __launch_bounds__(64) void k_ffn2(const float* __restrict__ w2,
                                             float* __restrict__ ws) {
  int l = blockIdx.x, b = blockIdx.y, c = threadIdx.x;
  __shared__ float hr[256];
  const float* hp = ws + OH1B + ((size_t)b * Ll + l) * 256;
  for (int i = c; i < 256; i += 64) hr[i] = hp[i];
  __syncthreads();
  float acc = 0.f;
  const float* wp = w2 + (size_t)c * 256;
#pragma unroll 8
  for (int mm = 0; mm < 256; ++mm) acc += hr[mm] * wp[mm];
  acc += ws[OX2 + ((size_t)b * Ll + l) * 64 + c];
  ws[OX3 + ((size_t)b * Ll + l) * 64 + c] = acc;
}

// ============ 13. transpose (B,L,C) -> (B,C,L) fp32 out ============
__global__ __launch_bounds__(256) void k_trout(const float* __restrict__ ws,
                                               float* __restrict__ out) {
  int b = blockIdx.y;
  int l0 = blockIdx.x * 64;
  int t = threadIdx.x;
  __shared__ float tile[64][65];
  const float* xp = ws + OX3 + ((size_t)b * Ll + l0) * 64;
  for (int i = t; i < 4096; i += 256) tile[i >> 6][i & 63] = xp[i];
  __syncthreads();
  for (int i = t; i < 4096; i += 256) {
    int c = i >> 6, li = i & 63;
    out[((size_t)(b * 64 + c)) * 2304 + l0 + li] = tile[li][c];
  }
}

extern "C" void kernel_launch(void* const* d_in, const int* in_sizes, int n_in,
                              void* d_out, int out_size, void* d_ws, size_t ws_size,
                              hipStream_t stream) {
  (void)in_sizes; (void)n_in; (void)out_size;
  const float* enc  = (const float*)d_in[0];
  const float* snr  = (const float*)d_in[1];
  const float* wq   = (const float*)d_in[2];
  const float* wk   = (const float*)d_in[3];
  const float* wv   = (const float*)d_in[4];
  const float* fc   = (const float*)d_in[5];
  const float* alnw = (const float*)d_in[6];
  const float* alnb = (const float*)d_in[7];
  const float* ssin = (const float*)d_in[8];
  const float* cw   = (const float*)d_in[9];
  const float* cb   = (const float*)d_in[10];
  const float* xw   = (const float*)d_in[11];
  const float* dtw  = (const float*)d_in[12];
  const float* dtb  = (const float*)d_in[13];
  const float* alog = (const float*)d_in[14];
  const float* Dp   = (const float*)d_in[15];
  const float* nw   = (const float*)d_in[16];
  const float* nb   = (const float*)d_in[17];
  const float* ow   = (const float*)d_in[18];
  const float* flnw = (const float*)d_in[19];
  const float* flnb = (const float*)d_in[20];
  const float* w1   = (const float*)d_in[21];
  const float* dww  = (const float*)d_in[22];
  const float* w2   = (const float*)d_in[23];
  float* ws = (float*)d_ws;
  float* out = (float*)d_out;

  if (ws_size < (size_t)WS_NEED_FLOATS * 4) {
    hipLaunchKernelGGL(k_code, dim3(1), dim3(64), 0, stream, out);
    return;
  }

  hipLaunchKernelGGL(k_qkv, dim3(Bq * Ll), dim3(256), 0, stream, enc, wq, wk, wv, ws);
  hipLaunchKernelGGL(k_vt, dim3(Ll / 64, Bq * NHh), dim3(256), 0, stream, ws);
  hipLaunchKernelGGL(k_attn, dim3(Ll / 64, Bq * NHh), dim3(256), 0, stream, snr, ws);
  hipLaunchKernelGGL(k_oprojxz, dim3(Ll, Bq), dim3(256), 0, stream, enc, fc, alnw, alnb, ssin, ws);
  hipLaunchKernelGGL(k_conv, dim3(Ll, Bq), dim3(128), 0, stream, cw, cb, ws);
  hipLaunchKernelGGL(k_xdbl, dim3(Ll, Bq * 4), dim3(128), 0, stream, xw, dtw, dtb, ws);
  hipLaunchKernelGGL(k_scanA, dim3(SNC, Bq * 4), dim3(256), 0, stream, alog, ws);
  hipLaunchKernelGGL(k_scanB, dim3(64), dim3(256), 0, stream, ws);
  hipLaunchKernelGGL(k_scanC, dim3(SNC, Bq * 4), dim3(256), 0, stream, alog, Dp, ws);
  hipLaunchKernelGGL(k_comb, dim3(Ll, Bq), dim3(128), 0, stream, nw, nb, snr, ws);
  hipLaunchKernelGGL(k_outffn1, dim3(Ll, Bq), dim3(256), 0, stream, enc, ow, flnw, flnb, w1, ws);
  hipLaunchKernelGGL(k_ffndw, dim3(Ll, Bq), dim3(256), 0, stream, dww, ws);
  hipLaunchKernelGGL(k_ffn2, dim3(Ll, Bq), dim3(64), 0, stream, w2, ws);
  hipLaunchKernelGGL(k_trout, dim3(Ll / 64, Bq), dim3(256), 0, stream, ws, out);
}

// Round 10
// 506.417 us; speedup vs baseline: 5.0481x; 1.2683x over previous
//
#include <hip/hip_runtime.h>
#include <hip/hip_bf16.h>

#define Bq 2
#define Cc 64
#define Hh 48
#define Ww 48
#define Ll 2304
#define NHh 8
#define DKk 64
#define DVv 128
#define DNn 128
#define NSs 16
#define Rr 4
#define SCH 48
#define SNC 48
#define TT 8      // tokens per block in GEMM-ish kernels

// ---- workspace layout (float offsets) ----
#define OQ    0u                 // (B*8, L, 64) Q bf16 (ushort), pre-scaled by 1/8
#define OK_   2359296u           // (B*8, L, 64) K bf16 (ushort)
#define OV    4718592u           // (B*8, L, 128) V fp32
#define OO    9437184u           // (B, L, 1024) attention out fp32
#define OY2   14450688u
#define OX2   15040512u
#define OXN   15335424u
#define OVT   15630336u          // (B*8, 128, L) V^T bf16 (ushort)
#define WS_NEED_FLOATS (OVT + 4718592u)
// aliases (lifetimes: q,k,v,vt dead after k_attn; o dead after k_oprojxz)
#define ODT2  OQ                 // (B*4, L, 128) dt, l-major
#define OYS2  OK_                // (B*4, L, 128) scan y, l-major
#define OX1P  OV                 // (B,L,128)
#define OZ    (OV + 589824u)     // (B,L,128)
#define OX1S  (OV + 1179648u)    // (B,L,128)
#define OBS2  (OV + 1769472u)    // (B*4, L, 16)
#define OCS2  (OV + 2064384u)    // (B*4, L, 16)
#define OCSA  (OV + 2359296u)    // (B*4, SNC, 128, 16)
#define OCSB  (OV + 3145728u)    // (B*4, SNC, 128, 16)
#define OHST  (OV + 3932160u)    // (B*4, SNC, 128, 16)
#define OH1A  OO                 // (B,L,256)
#define OH1B  (OO + 1179648u)    // (B,L,256)
#define OX3   (OO + 2359296u)    // (B,L,64)

typedef short short8v __attribute__((ext_vector_type(8)));
typedef short short4v __attribute__((ext_vector_type(4)));
typedef float f32x4 __attribute__((ext_vector_type(4)));
typedef unsigned short ushort_t;

__device__ __forceinline__ float geluf(float x) {
  return 0.5f * x * (1.0f + erff(x * 0.70710678118654752f));
}
__device__ __forceinline__ float siluf(float x) {
  return x / (1.0f + __expf(-x));
}
__device__ __forceinline__ float softplusf(float x) {
  return fmaxf(x, 0.0f) + log1pf(__expf(-fabsf(x)));
}
__device__ __forceinline__ int spmap(int k, int l) {
  if (k == 0) return l;
  if (k == 1) return (l % 48) * 48 + l / 48;
  if (k == 2) return 2303 - l;
  int l2 = 2303 - l; return (l2 % 48) * 48 + l2 / 48;
}
__device__ __forceinline__ short f2bf(float f) {
  unsigned u = __float_as_uint(f);
  unsigned r = (u + 0x7FFFu + ((u >> 16) & 1u)) >> 16;
  return (short)r;
}

__global__ void k_code(float* out) { if (threadIdx.x == 0) out[0] = 25000.f; }

// ============ 1. QKV projection, 8 tokens/block ============
__global__ __launch_bounds__(256) void k_qkv(const float* __restrict__ enc,
    const float* __restrict__ wq, const float* __restrict__ wk,
    const float* __restrict__ wv, float* __restrict__ ws) {
  int l0 = blockIdx.x * TT; int b = blockIdx.y;
  int t = threadIdx.x;
  __shared__ float xs[64][12];   // [c][token], pad 12 (16B-aligned rows)
  {
    int idx = t, c = idx >> 3, i = idx & 7;
    xs[c][i] = enc[(size_t)b * Cc * Ll + (size_t)c * Ll + l0 + i];
    idx = t + 256; c = idx >> 3; i = idx & 7;
    xs[c][i] = enc[(size_t)b * Cc * Ll + (size_t)c * Ll + l0 + i];
  }
  __syncthreads();
  ushort_t* qb = (ushort_t*)(ws + OQ);
  ushort_t* kb = (ushort_t*)(ws + OK_);
  float* v = ws + OV;
#pragma unroll
  for (int g = 0; g < 6; ++g) {
    int j = t + g * 256;
    float acc[TT];
#pragma unroll
    for (int i = 0; i < TT; ++i) acc[i] = 0.f;
    const float* wp; int col, stride;
    if (j < 512) { wp = wq + j; stride = 512; col = j; }
    else if (j < 1024) { wp = wk + (j - 512); stride = 512; col = j - 512; }
    else { wp = wv + (j - 1024); stride = 1024; col = j - 1024; }
    for (int c = 0; c < 64; ++c) {
      float w = wp[(size_t)c * stride];
      const float4* xc = (const float4*)&xs[c][0];
      float4 x0 = xc[0], x1 = xc[1];
      acc[0] += x0.x * w; acc[1] += x0.y * w;
      acc[2] += x0.z * w; acc[3] += x0.w * w;
      acc[4] += x1.x * w; acc[5] += x1.y * w;
      acc[6] += x1.z * w; acc[7] += x1.w * w;
    }
    if (j < 512) {
#pragma unroll
      for (int i = 0; i < TT; ++i)
        qb[((size_t)(b * 8 + (col >> 6)) * Ll + l0 + i) * 64 + (col & 63)] =
            (ushort_t)f2bf(acc[i] * 0.125f);
    } else if (j < 1024) {
#pragma unroll
      for (int i = 0; i < TT; ++i)
        kb[((size_t)(b * 8 + (col >> 6)) * Ll + l0 + i) * 64 + (col & 63)] =
            (ushort_t)f2bf(acc[i]);
    } else {
#pragma unroll
      for (int i = 0; i < TT; ++i)
        v[((size_t)(b * 8 + (col >> 7)) * Ll + l0 + i) * 128 + (col & 127)] = acc[i];
    }
  }
}

// ============ 1b. transpose V -> vt bf16 (bh, dv, L) ============
__global__ __launch_bounds__(256) void k_vt(float* __restrict__ ws) {
  int bh = blockIdx.y;
  int l0 = blockIdx.x * 64;
  int t = threadIdx.x;
  __shared__ float tile[128][65];
  const float* vp = ws + OV + ((size_t)bh * Ll + l0) * 128;
  for (int i = t; i < 64 * 32; i += 256) {
    int l = i >> 5, dv4 = (i & 31) * 4;
    float4 a = *(const float4*)(vp + (size_t)l * 128 + dv4);
    tile[dv4][l] = a.x; tile[dv4 + 1][l] = a.y;
    tile[dv4 + 2][l] = a.z; tile[dv4 + 3][l] = a.w;
  }
  __syncthreads();
  ushort_t* vt = (ushort_t*)(ws + OVT) + (size_t)bh * 128 * Ll + l0;
  for (int i = t; i < 128 * 16; i += 256) {
    int dv = i >> 4, l4 = (i & 15) * 4;
    short4v a;
    a[0] = f2bf(tile[dv][l4]); a[1] = f2bf(tile[dv][l4 + 1]);
    a[2] = f2bf(tile[dv][l4 + 2]); a[3] = f2bf(tile[dv][l4 + 3]);
    *(short4v*)(vt + (size_t)dv * Ll + l4) = a;
  }
}

// ============ 2. flash attention (bf16 MFMA, 64-key tiles, reg-prefetch) ============
#define NKT 36
#define LSK 72
__global__ __launch_bounds__(256) void k_attn(const float* __restrict__ snr,
                                              float* __restrict__ ws) {
  int bh = blockIdx.y; int b = bh >> 3; int hd = bh & 7;
  int q0 = blockIdx.x * 64;
  int t = threadIdx.x;
  int w = t >> 6, lane = t & 63;
  int m16 = lane & 15, quad = lane >> 4;

  __shared__ __align__(16) ushort_t Ks[64 * LSK];
  __shared__ __align__(16) ushort_t Vs[128 * LSK];
  __shared__ __align__(16) ushort_t Ps[4 * 16 * LSK];
  __shared__ float lsn_s[64];
  __shared__ float asc[4][16];
  __shared__ float lsc[4][16];

  const ushort_t* qbf = (const ushort_t*)(ws + OQ) + (size_t)bh * Ll * 64;
  const ushort_t* kbf = (const ushort_t*)(ws + OK_) + (size_t)bh * Ll * 64;
  const ushort_t* vtb = (const ushort_t*)(ws + OVT) + (size_t)bh * 128 * Ll;

  short8v qa[2];
  {
    const ushort_t* qrp = qbf + (size_t)(q0 + w * 16 + m16) * 64 + quad * 8;
    qa[0] = *(const short8v*)qrp;
    qa[1] = *(const short8v*)(qrp + 32);
  }
  int sk_key = t >> 2, sk_d0 = (t & 3) * 16;
  int sv_dv = t >> 1, sv_k0 = (t & 1) * 32;

  short8v kreg[2], vreg[4];
  float snr_reg = 0.f;
  {
    const ushort_t* ksrc = kbf + (size_t)sk_key * 64 + sk_d0;
    kreg[0] = *(const short8v*)ksrc;
    kreg[1] = *(const short8v*)(ksrc + 8);
    const ushort_t* vsrc = vtb + (size_t)sv_dv * Ll + sv_k0;
#pragma unroll
    for (int i = 0; i < 4; ++i) vreg[i] = *(const short8v*)(vsrc + i * 8);
    if (t < 64) snr_reg = snr[b * Ll + t];
  }

  f32x4 oacc[8];
#pragma unroll
  for (int i = 0; i < 8; ++i) oacc[i] = (f32x4)0.f;
  float m_r[4] = {-1e30f, -1e30f, -1e30f, -1e30f};
  float l_r[4] = {0.f, 0.f, 0.f, 0.f};

  for (int kt = 0; kt < NKT; ++kt) {
    __syncthreads();
    *(short8v*)&Ks[sk_key * LSK + sk_d0] = kreg[0];
    *(short8v*)&Ks[sk_key * LSK + sk_d0 + 8] = kreg[1];
#pragma unroll
    for (int i = 0; i < 4; ++i)
      *(short8v*)&Vs[sv_dv * LSK + sv_k0 + i * 8] = vreg[i];
    if (t < 64) lsn_s[t] = logf(snr_reg + 1e-4f);
    __syncthreads();
    if (kt + 1 < NKT) {
      int k0n = (kt + 1) * 64;
      const ushort_t* ksrc = kbf + (size_t)(k0n + sk_key) * 64 + sk_d0;
      kreg[0] = *(const short8v*)ksrc;
      kreg[1] = *(const short8v*)(ksrc + 8);
      const ushort_t* vsrc = vtb + (size_t)sv_dv * Ll + k0n + sv_k0;
#pragma unroll
      for (int i = 0; i < 4; ++i) vreg[i] = *(const short8v*)(vsrc + i * 8);
      if (t < 64) snr_reg = snr[b * Ll + k0n + t];
    }

    f32x4 sac[4];
#pragma unroll
    for (int n = 0; n < 4; ++n) {
      int key = n * 16 + m16;
      short8v kb0 = *(const short8v*)&Ks[key * LSK + quad * 8];
      short8v kb1 = *(const short8v*)&Ks[key * LSK + 32 + quad * 8];
      f32x4 acc = (f32x4)0.f;
      acc = __builtin_amdgcn_mfma_f32_16x16x32_bf16(qa[0], kb0, acc, 0, 0, 0);
      acc = __builtin_amdgcn_mfma_f32_16x16x32_bf16(qa[1], kb1, acc, 0, 0, 0);
      sac[n] = acc;
    }
    float lsv[4];
#pragma unroll
    for (int n = 0; n < 4; ++n) lsv[n] = lsn_s[n * 16 + m16];
    ushort_t* pw = &Ps[w * 16 * LSK];
    float alpha[4];
#pragma unroll
    for (int r = 0; r < 4; ++r) {
      float s[4], p[4];
#pragma unroll
      for (int n = 0; n < 4; ++n) s[n] = sac[n][r] + lsv[n];
      float mx = fmaxf(fmaxf(s[0], s[1]), fmaxf(s[2], s[3]));
      mx = fmaxf(mx, __shfl_xor(mx, 1, 64));
      mx = fmaxf(mx, __shfl_xor(mx, 2, 64));
      mx = fmaxf(mx, __shfl_xor(mx, 4, 64));
      mx = fmaxf(mx, __shfl_xor(mx, 8, 64));
      float nm = fmaxf(m_r[r], mx);
      alpha[r] = __expf(m_r[r] - nm);
      m_r[r] = nm;
      float rs = 0.f;
#pragma unroll
      for (int n = 0; n < 4; ++n) { p[n] = __expf(s[n] - nm); rs += p[n]; }
      rs += __shfl_xor(rs, 1, 64);
      rs += __shfl_xor(rs, 2, 64);
      rs += __shfl_xor(rs, 4, 64);
      rs += __shfl_xor(rs, 8, 64);
      l_r[r] = l_r[r] * alpha[r] + rs;
#pragma unroll
      for (int n = 0; n < 4; ++n)
        pw[(quad * 4 + r) * LSK + n * 16 + m16] = (ushort_t)f2bf(p[n]);
    }
    if (m16 == 0) {
#pragma unroll
      for (int r = 0; r < 4; ++r) asc[w][quad * 4 + r] = alpha[r];
    }
    float av = asc[w][m16];
    short8v pb0 = *(const short8v*)&pw[m16 * LSK + quad * 8];
    short8v pb1 = *(const short8v*)&pw[m16 * LSK + 32 + quad * 8];
#pragma unroll
    for (int dt_ = 0; dt_ < 8; ++dt_) {
      const ushort_t* vrow = &Vs[(dt_ * 16 + m16) * LSK];
      short8v va0 = *(const short8v*)&vrow[quad * 8];
      short8v va1 = *(const short8v*)&vrow[32 + quad * 8];
      f32x4 o = oacc[dt_];
      o[0] *= av; o[1] *= av; o[2] *= av; o[3] *= av;
      o = __builtin_amdgcn_mfma_f32_16x16x32_bf16(va0, pb0, o, 0, 0, 0);
      o = __builtin_amdgcn_mfma_f32_16x16x32_bf16(va1, pb1, o, 0, 0, 0);
      oacc[dt_] = o;
    }
  }
  if (m16 == 0) {
#pragma unroll
    for (int r = 0; r < 4; ++r) lsc[w][quad * 4 + r] = l_r[r];
  }
  float linv = 1.f / lsc[w][m16];
  float* op = ws + OO + ((size_t)(b * Ll + q0 + w * 16 + m16)) * 1024 + hd * 128;
#pragma unroll
  for (int dt_ = 0; dt_ < 8; ++dt_) {
#pragma unroll
    for (int r = 0; r < 4; ++r) {
      op[dt_ * 16 + quad * 4 + r] = oacc[dt_][r] * linv;
    }
  }
}

// ============ 3+4. o@fc + residual + LN + xz, 8 tokens/block ============
__global__ __launch_bounds__(256) void k_oprojxz(const float* __restrict__ enc,
    const float* __restrict__ fc, const float* __restrict__ lnw,
    const float* __restrict__ lnb, const float* __restrict__ ssin,
    float* __restrict__ ws) {
  int l0 = blockIdx.x * TT, b = blockIdx.y, t = threadIdx.x;
  __shared__ float orow[1024][9];   // [c][token], pad 9 (36 KB)
  __shared__ float part[4][TT][64];
  __shared__ float xh_s[64][9];
  const float* op = ws + OO + ((size_t)(b * Ll + l0)) * 1024;
#pragma unroll
  for (int k = 0; k < 4; ++k) {
    int c = t + k * 256;
#pragma unroll
    for (int i = 0; i < TT; ++i) orow[c][i] = op[(size_t)i * 1024 + c];
  }
  __syncthreads();
  int col = t & 63, seg = t >> 6;
  {
    float acc[TT];
#pragma unroll
    for (int i = 0; i < TT; ++i) acc[i] = 0.f;
    const float* fcs = fc + (size_t)(seg * 256) * 64 + col;
    for (int c = 0; c < 256; ++c) {
      float w = fcs[(size_t)c * 64];
      const float* orc = &orow[seg * 256 + c][0];
#pragma unroll
      for (int i = 0; i < TT; ++i) acc[i] += orc[i] * w;
    }
#pragma unroll
    for (int i = 0; i < TT; ++i) part[seg][i][col] = acc[i];
  }
  __syncthreads();
  if (t < 64) {
    float lw = lnw[t], lb = lnb[t];
#pragma unroll
    for (int i = 0; i < TT; ++i) {
      float a = part[0][i][t] + part[1][i][t] + part[2][i][t] + part[3][i][t];
      a += enc[(size_t)b * Cc * Ll + (size_t)t * Ll + l0 + i];
      float s = a;
#pragma unroll
      for (int o = 32; o >= 1; o >>= 1) s += __shfl_xor(s, o, 64);
      float m = s * (1.f / 64.f);
      float dd = a - m;
      float vs = dd * dd;
#pragma unroll
      for (int o = 32; o >= 1; o >>= 1) vs += __shfl_xor(vs, o, 64);
      xh_s[t][i] = dd * rsqrtf(vs * (1.f / 64.f) + 1e-5f) * lw + lb;
    }
  }
  __syncthreads();
  {
    float acc2[TT];
#pragma unroll
    for (int i = 0; i < TT; ++i) acc2[i] = 0.f;
    for (int c = 0; c < 64; ++c) {
      float w = ssin[c * 256 + t];
      const float* xc = &xh_s[c][0];
#pragma unroll
      for (int i = 0; i < TT; ++i) acc2[i] += xc[i] * w;
    }
    if (t < 128) {
#pragma unroll
      for (int i = 0; i < TT; ++i)
        ws[OX1P + ((size_t)(b * Ll + l0 + i)) * 128 + t] = acc2[i];
    } else {
#pragma unroll
      for (int i = 0; i < TT; ++i)
        ws[OZ + ((size_t)(b * Ll + l0 + i)) * 128 + (t - 128)] = acc2[i];
    }
  }
}

// ============ 5. depthwise conv3x3 + bias + silu ============
__global__ __launch_bounds__(128) void k_conv(const float* __restrict__ cw,
    const float* __restrict__ cb, float* __restrict__ ws) {
  int l = blockIdx.x, b = blockIdx.y, d = threadIdx.x;
  int h = l / 48, w = l % 48;
  float acc = cb[d];
#pragma unroll
  for (int kh = 0; kh < 3; ++kh) {
    int hh = h + kh - 1;
    if (hh < 0 || hh >= 48) continue;
#pragma unroll
    for (int kw = 0; kw < 3; ++kw) {
      int wx = w + kw - 1;
      if (wx < 0 || wx >= 48) continue;
      acc += ws[OX1P + ((size_t)b * Ll + hh * 48 + wx) * 128 + d] *
             cw[d * 9 + kh * 3 + kw];
    }
  }
  ws[OX1S + ((size_t)b * Ll + l) * 128 + d] = siluf(acc);
}

// ============ 6. x_dbl projections, 8 tokens/block ============
__global__ __launch_bounds__(128) void k_xdbl(const float* __restrict__ xw,
    const float* __restrict__ dtw, const float* __restrict__ dtb,
    float* __restrict__ ws) {
  int l0 = blockIdx.x * TT;
  int by = blockIdx.y; int b = by >> 2; int k = by & 3;
  int t = threadIdx.x;
  __shared__ float xv[128][9];   // [d][token]
  __shared__ float pr[36][TT];
#pragma unroll
  for (int i = 0; i < TT; ++i) {
    int sp = spmap(k, l0 + i);
    xv[t][i] = ws[OX1S + ((size_t)(b * Ll) + sp) * 128 + t];
  }
  __syncthreads();
  if (t < 36) {
    float s[TT];
#pragma unroll
    for (int i = 0; i < TT; ++i) s[i] = 0.f;
    const float* wp = xw + (size_t)(k * 36 + t) * 128;
    for (int d = 0; d < 128; ++d) {
      float w = wp[d];
      const float* xc = &xv[d][0];
#pragma unroll
      for (int i = 0; i < TT; ++i) s[i] += xc[i] * w;
    }
#pragma unroll
    for (int i = 0; i < TT; ++i) pr[t][i] = s[i];
  }
  __syncthreads();
  {
    int d = t;
    const float* wp = dtw + (size_t)(k * 128 + d) * 4;
    float w0 = wp[0], w1 = wp[1], w2 = wp[2], w3 = wp[3];
    float bb = dtb[k * 128 + d];
#pragma unroll
    for (int i = 0; i < TT; ++i) {
      float v = pr[0][i] * w0 + pr[1][i] * w1 + pr[2][i] * w2 + pr[3][i] * w3 + bb;
      ws[ODT2 + ((size_t)(by * Ll + l0 + i)) * 128 + d] = softplusf(v);
    }
  }
  if (t < 16) {
#pragma unroll
    for (int i = 0; i < TT; ++i)
      ws[OBS2 + ((size_t)(by * Ll + l0 + i)) * 16 + t] = pr[4 + t][i];
  } else if (t < 32) {
#pragma unroll
    for (int i = 0; i < TT; ++i)
      ws[OCS2 + ((size_t)(by * Ll + l0 + i)) * 16 + (t - 16)] = pr[20 + (t - 16)][i];
  }
}

// ============ 7a. scan phase A ============
__global__ __launch_bounds__(256) void k_scanA(const float* __restrict__ alog,
                                               float* __restrict__ ws) {
  int c = blockIdx.x;
  int bk = blockIdx.y;
  int b = bk >> 2, k = bk & 3;
  int t = threadIdx.x;
  int n = t & 15, dg = t >> 4;
  __shared__ float dt_s[128], x_s[128], Bs_s[16];
  float A_r[8], ap[8], bc[8];
#pragma unroll
  for (int i = 0; i < 8; ++i) {
    int d = dg * 8 + i;
    A_r[i] = -__expf(alog[(size_t)((k * 128 + d) * 16) + n]);
    ap[i] = 1.f; bc[i] = 0.f;
  }
  const float* dtp = ws + ODT2 + ((size_t)bk * Ll) * 128;
  const float* bsp = ws + OBS2 + ((size_t)bk * Ll) * 16;
  const float* xb = ws + OX1S + (size_t)b * Ll * 128;
  for (int ll = 0; ll < SCH; ++ll) {
    int l = c * SCH + ll;
    int sp = spmap(k, l);
    if (t < 128) dt_s[t] = dtp[(size_t)l * 128 + t];
    else x_s[t - 128] = xb[(size_t)sp * 128 + (t - 128)];
    if (t < 16) Bs_s[t] = bsp[(size_t)l * 16 + t];
    __syncthreads();
    float Bv = Bs_s[n];
#pragma unroll
    for (int i = 0; i < 8; ++i) {
      int d = dg * 8 + i;
      float dtv = dt_s[d];
      float a = __expf(dtv * A_r[i]);
      bc[i] = bc[i] * a + dtv * x_s[d] * Bv;
      ap[i] *= a;
    }
    __syncthreads();
  }
  float* csa = ws + OCSA + ((size_t)(bk * SNC + c) * 128) * 16;
  float* csb = ws + OCSB + ((size_t)(bk * SNC + c) * 128) * 16;
#pragma unroll
  for (int i = 0; i < 8; ++i) {
    int d = dg * 8 + i;
    csa[d * 16 + n] = ap[i];
    csb[d * 16 + n] = bc[i];
  }
}

// ============ 7b. scan phase B ============
__global__ __launch_bounds__(256) void k_scanB(float* __restrict__ ws) {
  int g = blockIdx.x * 256 + threadIdx.x;
  int bk = g >> 11;
  int dn = g & 2047;
  const float* csa = ws + OCSA;
  const float* csb = ws + OCSB;
  float* hst = ws + OHST;
  float h = 0.f;
  for (int c = 0; c < SNC; ++c) {
    size_t idx = (size_t)(bk * SNC + c) * 2048 + dn;
    hst[idx] = h;
    h = csa[idx] * h + csb[idx];
  }
}

// ============ 7c. scan phase C ============
__global__ __launch_bounds__(256) void k_scanC(const float* __restrict__ alog,
    const float* __restrict__ Dp, float* __restrict__ ws) {
  int c = blockIdx.x, bk = blockIdx.y;
  int b = bk >> 2, k = bk & 3;
  int t = threadIdx.x;
  int n = t & 15, dg = t >> 4;
  __shared__ float dt_s[128], x_s[128], Bs_s[16], Cs_s[16];
  float A_r[8], h[8], Dv[8];
#pragma unroll
  for (int i = 0; i < 8; ++i) {
    int d = dg * 8 + i;
    A_r[i] = -__expf(alog[(size_t)((k * 128 + d) * 16) + n]);
    h[i] = ws[OHST + ((size_t)(bk * SNC + c) * 128 + d) * 16 + n];
    Dv[i] = Dp[k * 128 + d];
  }
  const float* dtp = ws + ODT2 + ((size_t)bk * Ll) * 128;
  const float* bsp = ws + OBS2 + ((size_t)bk * Ll) * 16;
  const float* csp = ws + OCS2 + ((size_t)bk * Ll) * 16;
  const float* xb = ws + OX1S + (size_t)b * Ll * 128;
  float* yp = ws + OYS2 + ((size_t)bk * Ll) * 128;
  for (int ll = 0; ll < SCH; ++ll) {
    int l = c * SCH + ll;
    int sp = spmap(k, l);
    if (t < 128) dt_s[t] = dtp[(size_t)l * 128 + t];
    else x_s[t - 128] = xb[(size_t)sp * 128 + (t - 128)];
    if (t < 16) Bs_s[t] = bsp[(size_t)l * 16 + t];
    else if (t < 32) Cs_s[t - 16] = csp[(size_t)l * 16 + (t - 16)];
    __syncthreads();
    float Bv = Bs_s[n], Cv = Cs_s[n];
    float yacc[8];
#pragma unroll
    for (int i = 0; i < 8; ++i) {
      int d = dg * 8 + i;
      float dtv = dt_s[d];
      float a = __expf(dtv * A_r[i]);
      h[i] = h[i] * a + dtv * x_s[d] * Bv;
      yacc[i] = h[i] * Cv;
    }
#pragma unroll
    for (int i = 0; i < 8; ++i) {
      float yv = yacc[i];
      yv += __shfl_xor(yv, 1, 64);
      yv += __shfl_xor(yv, 2, 64);
      yv += __shfl_xor(yv, 4, 64);
      yv += __shfl_xor(yv, 8, 64);
      yacc[i] = yv;
    }
    if (n == 0) {
#pragma unroll
      for (int i = 0; i < 8; ++i) {
        int d = dg * 8 + i;
        yp[(size_t)l * 128 + d] = yacc[i] + Dv[i] * x_s[d];
      }
    }
    __syncthreads();
  }
}

// ============ 8. combine dirs + LN + gate ============
__global__ __launch_bounds__(128) void k_comb(const float* __restrict__ nw,
    const float* __restrict__ nb, const float* __restrict__ snr,
    float* __restrict__ ws) {
  int l = blockIdx.x, b = blockIdx.y, d = threadIdx.x;
  int h = l / 48, w = l % 48;
  int lT = w * 48 + h;
  const float* ysb = ws + OYS2;
  float v = ysb[((size_t)(b * 4 + 0) * Ll + l) * 128 + d] +
            ysb[((size_t)(b * 4 + 2) * Ll + (2303 - l)) * 128 + d] +
            ysb[((size_t)(b * 4 + 1) * Ll + lT) * 128 + d] +
            ysb[((size_t)(b * 4 + 3) * Ll + (2303 - lT)) * 128 + d];
  __shared__ float red[4];
  int lane = d & 63, wid = d >> 6;
  float s = v;
#pragma unroll
  for (int o = 32; o >= 1; o >>= 1) s += __shfl_xor(s, o, 64);
  if (lane == 0) red[wid] = s;
  __syncthreads();
  float m = (red[0] + red[1]) * (1.f / 128.f);
  float dv_ = v - m;
  float q = dv_ * dv_;
#pragma unroll
  for (int o = 32; o >= 1; o >>= 1) q += __shfl_xor(q, o, 64);
  if (lane == 0) red[wid + 2] = q;
  __syncthreads();
  float var = (red[2] + red[3]) * (1.f / 128.f);
  float y = dv_ * rsqrtf(var + 1e-5f) * nw[d] + nb[d];
  float zv = ws[OZ + ((size_t)b * Ll + l) * 128 + d];
  y *= siluf(zv);
  y *= snr[b * Ll + l];
  ws[OY2 + ((size_t)b * Ll + l) * 128 + d] = y;
}

// ============ 9+10. x2 + LN + FFN conv1 + gelu, 8 tokens/block ============
__global__ __launch_bounds__(256) void k_outffn1(const float* __restrict__ enc,
    const float* __restrict__ ow, const float* __restrict__ lw,
    const float* __restrict__ lb, const float* __restrict__ w1,
    float* __restrict__ ws) {
  int l0 = blockIdx.x * TT, b = blockIdx.y, t = threadIdx.x;
  __shared__ float yr[128][9];
  __shared__ float part[2][TT][64];
  __shared__ float xn_s[64][9];
  const float* yp = ws + OY2 + ((size_t)(b * Ll + l0)) * 128;
  if (t < 128) {
#pragma unroll
    for (int i = 0; i < TT; ++i) yr[t][i] = yp[(size_t)i * 128 + t];
  }
  __syncthreads();
  if (t < 128) {
    int col = t & 63, seg = t >> 6;
    float acc[TT];
#pragma unroll
    for (int i = 0; i < TT; ++i) acc[i] = 0.f;
    const float* ows = ow + (size_t)(seg * 64) * 64 + col;
    for (int c = 0; c < 64; ++c) {
      float w = ows[c * 64];
      const float* yc = &yr[seg * 64 + c][0];
#pragma unroll
      for (int i = 0; i < TT; ++i) acc[i] += yc[i] * w;
    }
#pragma unroll
    for (int i = 0; i < TT; ++i) part[seg][i][col] = acc[i];
  }
  __syncthreads();
  if (t < 64) {
    float lwv = lw[t], lbv = lb[t];
#pragma unroll
    for (int i = 0; i < TT; ++i) {
      float a = part[0][i][t] + part[1][i][t];
      a += enc[(size_t)b * Cc * Ll + (size_t)t * Ll + l0 + i];
      ws[OX2 + ((size_t)(b * Ll + l0 + i)) * 64 + t] = a;
      float s = a;
#pragma unroll
      for (int o = 32; o >= 1; o >>= 1) s += __shfl_xor(s, o, 64);
      float m = s * (1.f / 64.f);
      float dd2 = a - m;
      float vs = dd2 * dd2;
#pragma unroll
      for (int o = 32; o >= 1; o >>= 1) vs += __shfl_xor(vs, o, 64);
      xn_s[t][i] = dd2 * rsqrtf(vs * (1.f / 64.f) + 1e-5f) * lwv + lbv;
    }
  }
  __syncthreads();
  {
    float acc2[TT];
#pragma unroll
    for (int i = 0; i < TT; ++i) acc2[i] = 0.f;
    const float* wp = w1 + (size_t)t * 64;
    for (int c = 0; c < 64; ++c) {
      float w = wp[c];
      const float* xc = &xn_s[c][0];
#pragma unroll
      for (int i = 0; i < TT; ++i) acc2[i] += xc[i] * w;
    }
#pragma unroll
    for (int i = 0; i < TT; ++i)
      ws[OH1A + ((size_t)(b * Ll + l0 + i)) * 256 + t] = geluf(acc2[i]);
  }
}

// ============ 11. FFN depthwise 3x3 + gelu ============
__global__ __launch_bounds__(256) void k_ffndw(const float* __restrict__ dww,
                                               float* __restrict__ ws) {
  int l = blockIdx.x, b = blockIdx.y, mch = threadIdx.x;
  int h = l / 48, w = l % 48;
  float acc = 0.f;
#pragma unroll
  for (int kh = 0; kh < 3; ++kh) {
    int hh = h + kh - 1;
    if (hh < 0 || hh >= 48) continue;
#pragma unroll
    for (int kw = 0; kw < 3; ++kw) {
      int wx = w + kw - 1;
      if (wx < 0 || wx >= 48) continue;
      acc += ws[OH1A + ((size_t)b * Ll + hh * 48 + wx) * 256 + mch] *
             dww[mch * 9 + kh * 3 + kw];
    }
  }
  ws[OH1B + ((size_t)b * Ll + l) * 256 + mch] = geluf(acc);
}

// ============ 12. FFN conv2 1x1 + residual, 8 tokens/block ============
__global__ __launch_bounds__(256) void k_ffn2(const float* __restrict__ w2,
                                              float* __restrict__ ws) {
  int l0 = blockIdx.x * TT, b = blockIdx.y, t = threadIdx.x;
  __shared__ float hr[256][9];
  __shared__ float part[4][TT][64];
  const float* hp = ws + OH1B + ((size_t)(b * Ll + l0)) * 256;
#pragma unroll
  for (int i = 0; i < TT; ++i) hr[t][i] = hp[(size_t)i * 256 + t];
  __syncthreads();
  int col = t & 63, seg = t >> 6;
  {
    float acc[TT];
#pragma unroll
    for (int i = 0; i < TT; ++i) acc[i] = 0.f;
    const float* wp = w2 + (size_t)col * 256 + seg * 64;
    for (int c = 0; c < 64; ++c) {
      float w = wp[c];
      const float* hc = &hr[seg * 64 + c][0];
#pragma unroll
      for (int i = 0; i < TT; ++i) acc[i] += hc[i] * w;
    }
#pragma unroll
    for (int i = 0; i < TT; ++i) part[seg][i][col] = acc[i];
  }
  __syncthreads();
  if (t < 64) {
#pragma unroll
    for (int i = 0; i < TT; ++i) {
      float a = part[0][i][t] + part[1][i][t] + part[2][i][t] + part[3][i][t];
      a += ws[OX2 + ((size_t)(b * Ll + l0 + i)) * 64 + t];
      ws[OX3 + ((size_t)(b * Ll + l0 + i)) * 64 + t] = a;
    }
  }
}

// ============ 13. transpose (B,L,C) -> (B,C,L) fp32 out ============
__global__ __launch_bounds__(256) void k_trout(const float* __restrict__ ws,
                                               float* __restrict__ out) {
  int b = blockIdx.y;
  int l0 = blockIdx.x * 64;
  int t = threadIdx.x;
  __shared__ float tile[64][65];
  const float* xp = ws + OX3 + ((size_t)b * Ll + l0) * 64;
  for (int i = t; i < 4096; i += 256) tile[i >> 6][i & 63] = xp[i];
  __syncthreads();
  for (int i = t; i < 4096; i += 256) {
    int c = i >> 6, li = i & 63;
    out[((size_t)(b * 64 + c)) * 2304 + l0 + li] = tile[li][c];
  }
}

extern "C" void kernel_launch(void* const* d_in, const int* in_sizes, int n_in,
                              void* d_out, int out_size, void* d_ws, size_t ws_size,
                              hipStream_t stream) {
  (void)in_sizes; (void)n_in; (void)out_size;
  const float* enc  = (const float*)d_in[0];
  const float* snr  = (const float*)d_in[1];
  const float* wq   = (const float*)d_in[2];
  const float* wk   = (const float*)d_in[3];
  const float* wv   = (const float*)d_in[4];
  const float* fc   = (const float*)d_in[5];
  const float* alnw = (const float*)d_in[6];
  const float* alnb = (const float*)d_in[7];
  const float* ssin = (const float*)d_in[8];
  const float* cw   = (const float*)d_in[9];
  const float* cb   = (const float*)d_in[10];
  const float* xw   = (const float*)d_in[11];
  const float* dtw  = (const float*)d_in[12];
  const float* dtb  = (const float*)d_in[13];
  const float* alog = (const float*)d_in[14];
  const float* Dp   = (const float*)d_in[15];
  const float* nw   = (const float*)d_in[16];
  const float* nb   = (const float*)d_in[17];
  const float* ow   = (const float*)d_in[18];
  const float* flnw = (const float*)d_in[19];
  const float* flnb = (const float*)d_in[20];
  const float* w1   = (const float*)d_in[21];
  const float* dww  = (const float*)d_in[22];
  const float* w2   = (const float*)d_in[23];
  float* ws = (float*)d_ws;
  float* out = (float*)d_out;

  if (ws_size < (size_t)WS_NEED_FLOATS * 4) {
    hipLaunchKernelGGL(k_code, dim3(1), dim3(64), 0, stream, out);
    return;
  }

  hipLaunchKernelGGL(k_qkv, dim3(Ll / TT, Bq), dim3(256), 0, stream, enc, wq, wk, wv, ws);
  hipLaunchKernelGGL(k_vt, dim3(Ll / 64, Bq * NHh), dim3(256), 0, stream, ws);
  hipLaunchKernelGGL(k_attn, dim3(Ll / 64, Bq * NHh), dim3(256), 0, stream, snr, ws);
  hipLaunchKernelGGL(k_oprojxz, dim3(Ll / TT, Bq), dim3(256), 0, stream, enc, fc, alnw, alnb, ssin, ws);
  hipLaunchKernelGGL(k_conv, dim3(Ll, Bq), dim3(128), 0, stream, cw, cb, ws);
  hipLaunchKernelGGL(k_xdbl, dim3(Ll / TT, Bq * 4), dim3(128), 0, stream, xw, dtw, dtb, ws);
  hipLaunchKernelGGL(k_scanA, dim3(SNC, Bq * 4), dim3(256), 0, stream, alog, ws);
  hipLaunchKernelGGL(k_scanB, dim3(64), dim3(256), 0, stream, ws);
  hipLaunchKernelGGL(k_scanC, dim3(SNC, Bq * 4), dim3(256), 0, stream, alog, Dp, ws);
  hipLaunchKernelGGL(k_comb, dim3(Ll, Bq), dim3(128), 0, stream, nw, nb, snr, ws);
  hipLaunchKernelGGL(k_outffn1, dim3(Ll / TT, Bq), dim3(256), 0, stream, enc, ow, flnw, flnb, w1, ws);
  hipLaunchKernelGGL(k_ffndw, dim3(Ll, Bq), dim3(256), 0, stream, dww, ws);
  hipLaunchKernelGGL(k_ffn2, dim3(Ll / TT, Bq), dim3(256), 0, stream, w2, ws);
  hipLaunchKernelGGL(k_trout, dim3(Ll / 64, Bq), dim3(256), 0, stream, ws, out);
}